// Round 1
// baseline (4300.448 us; speedup 1.0000x reference)
//
#include <hip/hip_runtime.h>

#define NN 50000
#define HH 202
#define EE 100000
#define PMX 1024
#define ETY 6
#define BM 64
#define LDA 68   // 202-row LDS tile, padded leading dim: 16B-aligned, banks step by 4

__device__ __forceinline__ float sigf(float x) { return 1.0f / (1.0f + expf(-x)); }

// gate[p][j] = 2*sigmoid(sum_k pt[p][k]*pos_W[k][j] + pos_b[j])
__global__ void gate_kernel(const float* __restrict__ pos_W, const float* __restrict__ pos_b,
                            float* __restrict__ gate) {
    int p = blockIdx.x;
    __shared__ float pt[HH];
    int t = threadIdx.x;
    if (t < HH) {
        float v;
        if (t < 101) {
            float invf = expf(-(2.0f * t / 202.0f) * 9.210340371976184f); // ln(10000)
            v = sinf((float)p * invf);
        } else {
            int k = t - 101;
            float invf = expf(-(2.0f * k / 202.0f) * 9.210340371976184f);
            v = cosf((float)p * invf);
        }
        pt[t] = v;
    }
    __syncthreads();
    for (int j = t; j < HH; j += blockDim.x) {
        float acc = pos_b[j];
        for (int k = 0; k < HH; ++k) acc += pt[k] * pos_W[k * HH + j];
        gate[p * HH + j] = 2.0f * sigf(acc);
    }
}

// WT[k][r] = W[r][k]; W is [606][202]
__global__ void transpose_kernel(const float* __restrict__ W, float* __restrict__ WT) {
    int idx = blockIdx.x * blockDim.x + threadIdx.x;
    if (idx < 606 * HH) {
        int r = idx / HH, k = idx - r * HH;
        WT[k * 606 + r] = W[idx];
    }
}

__global__ void count_kernel(const int* __restrict__ el, float* __restrict__ cnt) {
    int idx = blockIdx.x * blockDim.x + threadIdx.x;
    if (idx >= ETY * EE) return;
    int ty = idx / EE, e = idx - ty * EE;
    int2 pr = (ty < 3) ? reinterpret_cast<const int2*>(el)[ty * EE + e]
                       : reinterpret_cast<const int2*>(el)[(ty - 3) * EE + e];
    int tg = (ty < 3) ? pr.y : pr.x;
    unsafeAtomicAdd(&cnt[tg], 1.0f);
}

__global__ void inv_kernel(float* __restrict__ cnt) {
    int n = blockIdx.x * blockDim.x + threadIdx.x;
    if (n < NN) cnt[n] = 1.0f / fmaxf(cnt[n], 1.0f);
}

// C[n][j] = A1[n][:] @ B1[:, j] (+ A2[n][:] @ B2[:, j]) + bias1[j] (+ bias2[j])
// A: [N,202] row-major; B: row k at B + k*ldb (caller applies column offset).
__global__ __launch_bounds__(256, 2) void gemm_kernel(
    const float* __restrict__ A1, const float* __restrict__ B1, int ldb1,
    const float* __restrict__ A2, const float* __restrict__ B2, int ldb2,
    const float* __restrict__ bias1, const float* __restrict__ bias2,
    float* __restrict__ C) {
    __shared__ float a_lds[HH * LDA];
    const int t = threadIdx.x;
    const int base = blockIdx.x * BM;
    const int j0 = t & 63;
    const int ns = t >> 6;   // wave id: wave-uniform A reads (LDS broadcast)

    float acc[16][4];
#pragma unroll
    for (int i = 0; i < 16; ++i) {
#pragma unroll
        for (int g = 0; g < 4; ++g) acc[i][g] = 0.0f;
    }

    const int npass = (A2 != nullptr) ? 2 : 1;
    for (int pass = 0; pass < npass; ++pass) {
        const float* A = pass ? A2 : A1;
        const float* B = pass ? B2 : B1;
        const int ldb = pass ? ldb2 : ldb1;
        if (pass) __syncthreads();
        // stage A tile transposed: a_lds[k][n] = A[base+n][k]
        for (int idx = t; idx < BM * 101; idx += 256) {
            int n = idx / 101;
            int kk = (idx - n * 101) * 2;
            int gn = base + n;
            float2 v = make_float2(0.0f, 0.0f);
            if (gn < NN) v = *reinterpret_cast<const float2*>(&A[gn * HH + kk]);
            a_lds[kk * LDA + n] = v.x;
            a_lds[(kk + 1) * LDA + n] = v.y;
        }
        __syncthreads();
        for (int k = 0; k < HH; ++k) {
            float b0 = B[k * ldb + j0];
            float b1 = B[k * ldb + j0 + 64];
            float b2 = B[k * ldb + j0 + 128];
            float b3 = (j0 < HH - 192) ? B[k * ldb + j0 + 192] : 0.0f;
            const float4* ar = reinterpret_cast<const float4*>(&a_lds[k * LDA + ns * 16]);
            float4 av0 = ar[0], av1 = ar[1], av2 = ar[2], av3 = ar[3];
            float av[16] = {av0.x, av0.y, av0.z, av0.w, av1.x, av1.y, av1.z, av1.w,
                            av2.x, av2.y, av2.z, av2.w, av3.x, av3.y, av3.z, av3.w};
#pragma unroll
            for (int i = 0; i < 16; ++i) {
                acc[i][0] = fmaf(av[i], b0, acc[i][0]);
                acc[i][1] = fmaf(av[i], b1, acc[i][1]);
                acc[i][2] = fmaf(av[i], b2, acc[i][2]);
                acc[i][3] = fmaf(av[i], b3, acc[i][3]);
            }
        }
    }

    const bool hb2 = (bias2 != nullptr);
#pragma unroll
    for (int i = 0; i < 16; ++i) {
        int n = base + ns * 16 + i;
        if (n < NN) {
            float* crow = C + (size_t)n * HH;
#pragma unroll
            for (int g = 0; g < 4; ++g) {
                int j = g * 64 + j0;
                if (j < HH) {
                    float b = bias1[j] + (hb2 ? bias2[j] : 0.0f);
                    crow[j] = acc[i][g] + b;
                }
            }
        }
    }
}

// one wave per edge: msg[tgt] += chunk[src] * gate[pos]
__global__ void scatter_kernel(const float* __restrict__ chunk, const float* __restrict__ gate,
                               const int* __restrict__ el, const int* __restrict__ pl,
                               int ty, float* __restrict__ msg) {
    int gid = blockIdx.x * blockDim.x + threadIdx.x;
    int e = gid >> 6;
    int lane = gid & 63;
    if (e >= EE) return;
    int s, tg;
    if (ty < 3) {
        int2 pr = reinterpret_cast<const int2*>(el)[ty * EE + e];
        s = pr.x; tg = pr.y;
    } else {
        int2 pr = reinterpret_cast<const int2*>(el)[(ty - 3) * EE + e];
        s = pr.y; tg = pr.x;
    }
    int p = pl[(ty % 3) * EE + e];
    p = min(max(p, 0), PMX - 1);
    const float* cr = chunk + (size_t)s * HH;
    const float* gr = gate + (size_t)p * HH;
    float* mr = msg + (size_t)tg * HH;
    for (int j = lane; j < HH; j += 64)
        unsafeAtomicAdd(&mr[j], cr[j] * gr[j]);
}

__global__ void scale_kernel(float* __restrict__ msg, const float* __restrict__ inv) {
    int idx = blockIdx.x * blockDim.x + threadIdx.x;
    if (idx < NN * HH) msg[idx] *= inv[idx / HH];
}

// nval(io=hn) = tanh(inn + sigmoid(sr)*hn)
__global__ void ew_n_kernel(float* __restrict__ hn_io, const float* __restrict__ inn,
                            const float* __restrict__ sr) {
    int idx = blockIdx.x * blockDim.x + threadIdx.x;
    if (idx < NN * HH) {
        float r = sigf(sr[idx]);
        hn_io[idx] = tanhf(inn[idx] + r * hn_io[idx]);
    }
}

// h = (1-z)*n + z*h
__global__ void ew_h_kernel(float* __restrict__ h, const float* __restrict__ nval,
                            const float* __restrict__ sz) {
    int idx = blockIdx.x * blockDim.x + threadIdx.x;
    if (idx < NN * HH) {
        float z = sigf(sz[idx]);
        h[idx] = (1.0f - z) * nval[idx] + z * h[idx];
    }
}

extern "C" void kernel_launch(void* const* d_in, const int* in_sizes, int n_in,
                              void* d_out, int out_size, void* d_ws, size_t ws_size,
                              hipStream_t stream) {
    const float* node_states = (const float*)d_in[0];
    const int*   el          = (const int*)d_in[1];
    const int*   pl          = (const int*)d_in[2];
    const float* msg_W       = (const float*)d_in[3];
    const float* msg_b       = (const float*)d_in[4];
    const float* pos_W       = (const float*)d_in[5];
    const float* pos_b       = (const float*)d_in[6];
    const float* gWih        = (const float*)d_in[7];
    const float* gWhh        = (const float*)d_in[8];
    const float* gbih        = (const float*)d_in[9];
    const float* gbhh        = (const float*)d_in[10];

    float* out  = (float*)d_out;
    float* h    = out;                          // [N,H] final h lives here
    float* out2 = out + (size_t)NN * HH;        // scratch (sr), node_states copy at end

    float* ws   = (float*)d_ws;
    float* CB   = ws;                           // [N,H] prop chunk / hn / n
    float* MSG  = CB + (size_t)NN * HH;         // [N,H] messages
    float* B2   = MSG + (size_t)NN * HH;        // [N,H] inn / sz
    float* GATE = B2 + (size_t)NN * HH;         // [1024,H]
    float* INV  = GATE + (size_t)PMX * HH;      // [N]
    float* WIHT = INV + NN;                     // [202][606]
    float* WHHT = WIHT + (size_t)HH * 606;      // [202][606]

    const size_t NH = (size_t)NN * HH;
    hipMemcpyAsync(h, node_states, NH * sizeof(float), hipMemcpyDeviceToDevice, stream);
    hipMemsetAsync(INV, 0, NN * sizeof(float), stream);
    gate_kernel<<<PMX, 256, 0, stream>>>(pos_W, pos_b, GATE);
    transpose_kernel<<<(606 * HH + 255) / 256, 256, 0, stream>>>(gWih, WIHT);
    transpose_kernel<<<(606 * HH + 255) / 256, 256, 0, stream>>>(gWhh, WHHT);
    count_kernel<<<(ETY * EE + 255) / 256, 256, 0, stream>>>(el, INV);
    inv_kernel<<<(NN + 255) / 256, 256, 0, stream>>>(INV);

    const int gblocks = (NN + BM - 1) / BM;     // 782
    const int ewblocks = (NN * HH + 255) / 256;
    for (int step = 0; step < 2; ++step) {
        hipMemsetAsync(MSG, 0, NH * sizeof(float), stream);
        for (int ty = 0; ty < ETY; ++ty) {
            gemm_kernel<<<gblocks, 256, 0, stream>>>(
                h, msg_W + ty * HH, 1212, nullptr, nullptr, 0,
                msg_b + ty * HH, nullptr, CB);
            scatter_kernel<<<(EE * 64 + 255) / 256, 256, 0, stream>>>(
                CB, GATE, el, pl, ty, MSG);
        }
        scale_kernel<<<ewblocks, 256, 0, stream>>>(MSG, INV);
        // hn -> CB
        gemm_kernel<<<gblocks, 256, 0, stream>>>(
            h, WHHT + 404, 606, nullptr, nullptr, 0, gbhh + 404, nullptr, CB);
        // inn -> B2
        gemm_kernel<<<gblocks, 256, 0, stream>>>(
            MSG, WIHT + 404, 606, nullptr, nullptr, 0, gbih + 404, nullptr, B2);
        // sr = ir + hr -> out2
        gemm_kernel<<<gblocks, 256, 0, stream>>>(
            MSG, WIHT, 606, h, WHHT, 606, gbih, gbhh, out2);
        // n = tanh(inn + sigmoid(sr)*hn) -> CB
        ew_n_kernel<<<ewblocks, 256, 0, stream>>>(CB, B2, out2);
        // sz = iz + hz -> B2
        gemm_kernel<<<gblocks, 256, 0, stream>>>(
            MSG, WIHT + 202, 606, h, WHHT + 202, 606, gbih + 202, gbhh + 202, B2);
        // h = (1-z)*n + z*h
        ew_h_kernel<<<ewblocks, 256, 0, stream>>>(h, CB, B2);
    }
    hipMemcpyAsync(out2, node_states, NH * sizeof(float), hipMemcpyDeviceToDevice, stream);
}

// Round 2
// 2160.188 us; speedup vs baseline: 1.9908x; 1.9908x over previous
//
#include <hip/hip_runtime.h>

#define NN 50000
#define HH 202
#define EE 100000
#define PMX 1024
#define ETY 6
#define KP 224         // K padded to 7*32
#define NKT 7          // k-steps of 32
#define NF 13          // 16-col fragments covering 202 cols (13*16=208)
#define LDA 232        // LDS A row stride (ushort elems)
#define PKSZ (NF * NKT * 64 * 8)   // ushorts per B pack = 46592

typedef __attribute__((ext_vector_type(8))) short short8;
typedef __attribute__((ext_vector_type(4))) float v4f;

__device__ __forceinline__ float sigf(float x) { return 1.0f / (1.0f + expf(-x)); }

__device__ __forceinline__ unsigned short f2bf(float x) {
    unsigned int u = __float_as_uint(x);
    unsigned int r = (u + 0x7fffu + ((u >> 16) & 1u)) >> 16;
    return (unsigned short)r;
}

// gate[p][j] = 2*sigmoid(sum_k pt[p][k]*pos_W[k][j] + pos_b[j])
__global__ void gate_kernel(const float* __restrict__ pos_W, const float* __restrict__ pos_b,
                            float* __restrict__ gate) {
    int p = blockIdx.x;
    __shared__ float pt[HH];
    int t = threadIdx.x;
    if (t < HH) {
        float v;
        if (t < 101) {
            float invf = expf(-(2.0f * t / 202.0f) * 9.210340371976184f); // ln(10000)
            v = sinf((float)p * invf);
        } else {
            int k = t - 101;
            float invf = expf(-(2.0f * k / 202.0f) * 9.210340371976184f);
            v = cosf((float)p * invf);
        }
        pt[t] = v;
    }
    __syncthreads();
    for (int j = t; j < HH; j += blockDim.x) {
        float acc = pos_b[j];
        for (int k = 0; k < HH; ++k) acc += pt[k] * pos_W[k * HH + j];
        gate[p * HH + j] = 2.0f * sigf(acc);
    }
}

__global__ void count_kernel(const int* __restrict__ el, float* __restrict__ cnt) {
    int idx = blockIdx.x * blockDim.x + threadIdx.x;
    if (idx >= ETY * EE) return;
    int ty = idx / EE, e = idx - ty * EE;
    int2 pr = (ty < 3) ? reinterpret_cast<const int2*>(el)[ty * EE + e]
                       : reinterpret_cast<const int2*>(el)[(ty - 3) * EE + e];
    int tg = (ty < 3) ? pr.y : pr.x;
    unsafeAtomicAdd(&cnt[tg], 1.0f);
}

__global__ void inv_kernel(float* __restrict__ cnt) {
    int n = blockIdx.x * blockDim.x + threadIdx.x;
    if (n < NN) cnt[n] = 1.0f / fmaxf(cnt[n], 1.0f);
}

// Pack B into MFMA fragment order, f32 -> bf16.
// BP[((cf*NKT + kt)*64 + l)*8 + jj] = B[k][j], k = kt*32 + (l>>4)*8 + jj, j = cf*16 + (l&15)
// mode 0: B[k][j] = S[k*ldb + col0 + j]          (msg_W row-major)
// mode 1: B[k][j] = S[(row0 + j)*HH + k]         (GRU W [606][202], transposed use)
__global__ void pack_kernel(const float* __restrict__ S, int ldb, int row0, int col0, int mode,
                            unsigned short* __restrict__ BP) {
    int idx = blockIdx.x * blockDim.x + threadIdx.x;
    if (idx >= PKSZ) return;
    int jj = idx & 7;
    int l = (idx >> 3) & 63;
    int r2 = idx >> 9;             // cf*NKT + kt
    int cf = r2 / NKT, kt = r2 - cf * NKT;
    int k = kt * 32 + ((l >> 4) << 3) + jj;
    int j = cf * 16 + (l & 15);
    float v = 0.0f;
    if (k < HH && j < HH)
        v = mode ? S[(size_t)(row0 + j) * HH + k] : S[(size_t)k * ldb + col0 + j];
    BP[idx] = f2bf(v);
}

// C[64 rows][202 cols] = A1 @ B1 (+ A2 @ B2) + bias1 (+ bias2), bf16 MFMA, f32 accum.
// A: f32 [N][202] row-major, converted to bf16 while staging to LDS.
// BP: fragment-packed bf16 (see pack_kernel).
__global__ __launch_bounds__(256) void gemm_mfma(
    const float* __restrict__ A1, const unsigned short* __restrict__ BP1,
    const float* __restrict__ A2, const unsigned short* __restrict__ BP2,
    const float* __restrict__ bias1, const float* __restrict__ bias2,
    float* __restrict__ C) {
    __shared__ unsigned short a_lds[64 * LDA];
    const int t = threadIdx.x;
    const int w = t >> 6;
    const int l = t & 63;
    const int lm = l & 15, lh = l >> 4;
    const int base = blockIdx.x * 64;
    const int nf = (w == 0) ? 4 : 3;   // wave w owns col frags {w, w+4, w+8, (w+12)}

    v4f acc[4][4];
#pragma unroll
    for (int i = 0; i < 4; ++i)
#pragma unroll
        for (int fi = 0; fi < 4; ++fi) acc[i][fi] = (v4f){0.f, 0.f, 0.f, 0.f};

    const int npass = (A2 != nullptr) ? 2 : 1;
    for (int pass = 0; pass < npass; ++pass) {
        const float* A = pass ? A2 : A1;
        const unsigned short* BP = pass ? BP2 : BP1;
        if (pass) __syncthreads();
        // stage A tile (f32 -> bf16), 64 rows x 101 float2 chunks
        for (int idx = t; idx < 64 * 101; idx += 256) {
            int row = idx / 101;
            int c = idx - row * 101;
            int gn = base + row;
            float2 v = make_float2(0.f, 0.f);
            if (gn < NN) v = *reinterpret_cast<const float2*>(&A[(size_t)gn * HH + c * 2]);
            ushort2 bv;
            bv.x = f2bf(v.x);
            bv.y = f2bf(v.y);
            *reinterpret_cast<ushort2*>(&a_lds[row * LDA + c * 2]) = bv;
        }
        // zero K-pad 202..223
        for (int idx = t; idx < 64 * 11; idx += 256) {
            int row = idx / 11;
            int c = idx - row * 11;
            ushort2 z; z.x = 0; z.y = 0;
            *reinterpret_cast<ushort2*>(&a_lds[row * LDA + HH + c * 2]) = z;
        }
        __syncthreads();

#pragma unroll
        for (int kt = 0; kt < NKT; ++kt) {
            short8 a[4];
#pragma unroll
            for (int fi = 0; fi < 4; ++fi)
                a[fi] = *reinterpret_cast<const short8*>(
                    &a_lds[(fi * 16 + lm) * LDA + kt * 32 + lh * 8]);
#pragma unroll
            for (int i = 0; i < 4; ++i) {
                if (i < nf) {
                    int cf = w + 4 * i;
                    short8 b = *reinterpret_cast<const short8*>(
                        &BP[((cf * NKT + kt) * 64 + l) * 8]);
#pragma unroll
                    for (int fi = 0; fi < 4; ++fi)
                        acc[i][fi] = __builtin_amdgcn_mfma_f32_16x16x32_bf16(
                            a[fi], b, acc[i][fi], 0, 0, 0);
                }
            }
        }
    }

    const bool hb2 = (bias2 != nullptr);
#pragma unroll
    for (int i = 0; i < 4; ++i) {
        if (i < nf) {
            int jc = (w + 4 * i) * 16 + lm;
            if (jc < HH) {
                float bv = bias1[jc] + (hb2 ? bias2[jc] : 0.0f);
#pragma unroll
                for (int fi = 0; fi < 4; ++fi) {
#pragma unroll
                    for (int r = 0; r < 4; ++r) {
                        int row = base + fi * 16 + lh * 4 + r;
                        if (row < NN) C[(size_t)row * HH + jc] = acc[i][fi][r] + bv;
                    }
                }
            }
        }
    }
}

// one wave per edge: msg[tgt] += chunk[src] * gate[pos]
__global__ void scatter_kernel(const float* __restrict__ chunk, const float* __restrict__ gate,
                               const int* __restrict__ el, const int* __restrict__ pl,
                               int ty, float* __restrict__ msg) {
    int gid = blockIdx.x * blockDim.x + threadIdx.x;
    int e = gid >> 6;
    int lane = gid & 63;
    if (e >= EE) return;
    int s, tg;
    if (ty < 3) {
        int2 pr = reinterpret_cast<const int2*>(el)[ty * EE + e];
        s = pr.x; tg = pr.y;
    } else {
        int2 pr = reinterpret_cast<const int2*>(el)[(ty - 3) * EE + e];
        s = pr.y; tg = pr.x;
    }
    int p = pl[(ty % 3) * EE + e];
    p = min(max(p, 0), PMX - 1);
    const float* cr = chunk + (size_t)s * HH;
    const float* gr = gate + (size_t)p * HH;
    float* mr = msg + (size_t)tg * HH;
    for (int j = lane; j < HH; j += 64)
        unsafeAtomicAdd(&mr[j], cr[j] * gr[j]);
}

__global__ void scale_kernel(float* __restrict__ msg, const float* __restrict__ inv) {
    int idx = blockIdx.x * blockDim.x + threadIdx.x;
    if (idx < NN * HH) msg[idx] *= inv[idx / HH];
}

// nval(io=hn) = tanh(inn + sigmoid(sr)*hn)
__global__ void ew_n_kernel(float* __restrict__ hn_io, const float* __restrict__ inn,
                            const float* __restrict__ sr) {
    int idx = blockIdx.x * blockDim.x + threadIdx.x;
    if (idx < NN * HH) {
        float r = sigf(sr[idx]);
        hn_io[idx] = tanhf(inn[idx] + r * hn_io[idx]);
    }
}

// h = (1-z)*n + z*h
__global__ void ew_h_kernel(float* __restrict__ h, const float* __restrict__ nval,
                            const float* __restrict__ sz) {
    int idx = blockIdx.x * blockDim.x + threadIdx.x;
    if (idx < NN * HH) {
        float z = sigf(sz[idx]);
        h[idx] = (1.0f - z) * nval[idx] + z * h[idx];
    }
}

extern "C" void kernel_launch(void* const* d_in, const int* in_sizes, int n_in,
                              void* d_out, int out_size, void* d_ws, size_t ws_size,
                              hipStream_t stream) {
    const float* node_states = (const float*)d_in[0];
    const int*   el          = (const int*)d_in[1];
    const int*   pl          = (const int*)d_in[2];
    const float* msg_W       = (const float*)d_in[3];
    const float* msg_b       = (const float*)d_in[4];
    const float* pos_W       = (const float*)d_in[5];
    const float* pos_b       = (const float*)d_in[6];
    const float* gWih        = (const float*)d_in[7];
    const float* gWhh        = (const float*)d_in[8];
    const float* gbih        = (const float*)d_in[9];
    const float* gbhh        = (const float*)d_in[10];

    float* out  = (float*)d_out;
    float* h    = out;                          // [N,H] final h
    float* out2 = out + (size_t)NN * HH;        // scratch (sr), node_states copy at end

    float* ws   = (float*)d_ws;
    float* CB   = ws;                           // [N,H] prop chunk / hn / n
    float* MSG  = CB + (size_t)NN * HH;         // [N,H] messages
    float* B2   = MSG + (size_t)NN * HH;        // [N,H] inn / sz
    float* GATE = B2 + (size_t)NN * HH;         // [1024,H]
    float* INV  = GATE + (size_t)PMX * HH;      // [N]
    unsigned short* BPA = (unsigned short*)(INV + NN);  // 12 packs
    unsigned short* BPp  = BPA;                 // 6 prop packs
    unsigned short* BPir = BPA + (size_t)6 * PKSZ;
    unsigned short* BPiz = BPA + (size_t)7 * PKSZ;
    unsigned short* BPin = BPA + (size_t)8 * PKSZ;
    unsigned short* BPhr = BPA + (size_t)9 * PKSZ;
    unsigned short* BPhz = BPA + (size_t)10 * PKSZ;
    unsigned short* BPhn = BPA + (size_t)11 * PKSZ;

    const size_t NH = (size_t)NN * HH;
    hipMemcpyAsync(h, node_states, NH * sizeof(float), hipMemcpyDeviceToDevice, stream);
    hipMemsetAsync(INV, 0, NN * sizeof(float), stream);
    gate_kernel<<<PMX, 256, 0, stream>>>(pos_W, pos_b, GATE);
    const int pkb = (PKSZ + 255) / 256;
    for (int ty = 0; ty < ETY; ++ty)
        pack_kernel<<<pkb, 256, 0, stream>>>(msg_W, 1212, 0, ty * HH, 0, BPp + (size_t)ty * PKSZ);
    pack_kernel<<<pkb, 256, 0, stream>>>(gWih, 0, 0,   0, 1, BPir);
    pack_kernel<<<pkb, 256, 0, stream>>>(gWih, 0, 202, 0, 1, BPiz);
    pack_kernel<<<pkb, 256, 0, stream>>>(gWih, 0, 404, 0, 1, BPin);
    pack_kernel<<<pkb, 256, 0, stream>>>(gWhh, 0, 0,   0, 1, BPhr);
    pack_kernel<<<pkb, 256, 0, stream>>>(gWhh, 0, 202, 0, 1, BPhz);
    pack_kernel<<<pkb, 256, 0, stream>>>(gWhh, 0, 404, 0, 1, BPhn);
    count_kernel<<<(ETY * EE + 255) / 256, 256, 0, stream>>>(el, INV);
    inv_kernel<<<(NN + 255) / 256, 256, 0, stream>>>(INV);

    const int gblocks = (NN + 63) / 64;        // 782
    const int ewblocks = (NN * HH + 255) / 256;
    for (int step = 0; step < 2; ++step) {
        hipMemsetAsync(MSG, 0, NH * sizeof(float), stream);
        for (int ty = 0; ty < ETY; ++ty) {
            gemm_mfma<<<gblocks, 256, 0, stream>>>(
                h, BPp + (size_t)ty * PKSZ, nullptr, nullptr,
                msg_b + ty * HH, nullptr, CB);
            scatter_kernel<<<(EE * 64 + 255) / 256, 256, 0, stream>>>(
                CB, GATE, el, pl, ty, MSG);
        }
        scale_kernel<<<ewblocks, 256, 0, stream>>>(MSG, INV);
        // hn -> CB
        gemm_mfma<<<gblocks, 256, 0, stream>>>(
            h, BPhn, nullptr, nullptr, gbhh + 404, nullptr, CB);
        // inn -> B2
        gemm_mfma<<<gblocks, 256, 0, stream>>>(
            MSG, BPin, nullptr, nullptr, gbih + 404, nullptr, B2);
        // sr = ir + hr -> out2
        gemm_mfma<<<gblocks, 256, 0, stream>>>(
            MSG, BPir, h, BPhr, gbih, gbhh, out2);
        // n = tanh(inn + sigmoid(sr)*hn) -> CB
        ew_n_kernel<<<ewblocks, 256, 0, stream>>>(CB, B2, out2);
        // sz = iz + hz -> B2
        gemm_mfma<<<gblocks, 256, 0, stream>>>(
            MSG, BPiz, h, BPhz, gbih + 202, gbhh + 202, B2);
        // h = (1-z)*n + z*h
        ew_h_kernel<<<ewblocks, 256, 0, stream>>>(h, CB, B2);
    }
    hipMemcpyAsync(out2, node_states, NH * sizeof(float), hipMemcpyDeviceToDevice, stream);
}

// Round 3
// 1126.918 us; speedup vs baseline: 3.8161x; 1.9169x over previous
//
#include <hip/hip_runtime.h>

#define NN 50000
#define HH 202
#define EE 100000
#define PMX 1024
#define NKT 7          // k-steps of 32 (K padded to 224)
#define LDA 232        // LDS A row stride in ushorts (464 B: 116 dwords %32=20 -> 2-way max)
#define PKSZ (13 * NKT * 64 * 8)   // ushorts per B pack = 46592
#define NEDG (6 * EE)

typedef __attribute__((ext_vector_type(8))) short short8;
typedef __attribute__((ext_vector_type(4))) float v4f;

__device__ __forceinline__ float sigf(float x) { return 1.0f / (1.0f + expf(-x)); }

__device__ __forceinline__ unsigned short f2bf(float x) {
    unsigned int u = __float_as_uint(x);
    unsigned int r = (u + 0x7fffu + ((u >> 16) & 1u)) >> 16;
    return (unsigned short)r;
}
__device__ __forceinline__ float bf2f(unsigned short u) {
    return __uint_as_float(((unsigned int)u) << 16);
}

// gate[p][j] = bf16( 2*sigmoid(sum_k pt[p][k]*pos_W[k][j] + pos_b[j]) )
__global__ void gate_kernel(const float* __restrict__ pos_W, const float* __restrict__ pos_b,
                            unsigned short* __restrict__ gate) {
    int p = blockIdx.x;
    __shared__ float pt[HH];
    int t = threadIdx.x;
    if (t < HH) {
        float v;
        if (t < 101) {
            float invf = expf(-(2.0f * t / 202.0f) * 9.210340371976184f); // ln(10000)
            v = sinf((float)p * invf);
        } else {
            int k = t - 101;
            float invf = expf(-(2.0f * k / 202.0f) * 9.210340371976184f);
            v = cosf((float)p * invf);
        }
        pt[t] = v;
    }
    __syncthreads();
    for (int j = t; j < HH; j += blockDim.x) {
        float acc = pos_b[j];
        for (int k = 0; k < HH; ++k) acc += pt[k] * pos_W[k * HH + j];
        gate[p * HH + j] = f2bf(2.0f * sigf(acc));
    }
}

// Pack B into MFMA fragment order, f32 -> bf16.
// BP[((cf*NKT + kt)*64 + l)*8 + jj] = B[k][j], k = kt*32 + (l>>4)*8 + jj, j = cf*16 + (l&15)
// mode 0: B[k][j] = S[k*ldb + col0 + j]          (msg_W row-major)
// mode 1: B[k][j] = S[(row0 + j)*HH + k]         (GRU W [606][202], transposed use)
__global__ void pack_kernel(const float* __restrict__ S, int ldb, int row0, int col0, int mode,
                            unsigned short* __restrict__ BP) {
    int idx = blockIdx.x * blockDim.x + threadIdx.x;
    if (idx >= PKSZ) return;
    int jj = idx & 7;
    int l = (idx >> 3) & 63;
    int r2 = idx >> 9;             // cf*NKT + kt
    int cf = r2 / NKT, kt = r2 - cf * NKT;
    int k = kt * 32 + ((l >> 4) << 3) + jj;
    int j = cf * 16 + (l & 15);
    float v = 0.0f;
    if (k < HH && j < HH)
        v = mode ? S[(size_t)(row0 + j) * HH + k] : S[(size_t)k * ldb + col0 + j];
    BP[idx] = f2bf(v);
}

__global__ void count_kernel(const int* __restrict__ el, int* __restrict__ cnt) {
    int idx = blockIdx.x * blockDim.x + threadIdx.x;
    if (idx >= NEDG) return;
    int ty = idx / EE, e = idx - ty * EE;
    int2 pr = (ty < 3) ? reinterpret_cast<const int2*>(el)[ty * EE + e]
                       : reinterpret_cast<const int2*>(el)[(ty - 3) * EE + e];
    int tg = (ty < 3) ? pr.y : pr.x;
    atomicAdd(&cnt[tg], 1);
}

__global__ void scan1_kernel(const int* __restrict__ cnt, int* __restrict__ off,
                             int* __restrict__ bsum) {
    __shared__ int sd[256];
    int t = threadIdx.x, i = blockIdx.x * 256 + t;
    int v = (i < NN) ? cnt[i] : 0;
    sd[t] = v;
    __syncthreads();
    for (int s = 1; s < 256; s <<= 1) {
        int u = (t >= s) ? sd[t - s] : 0;
        __syncthreads();
        sd[t] += u;
        __syncthreads();
    }
    if (i < NN) off[i] = sd[t] - v;
    if (t == 255) bsum[blockIdx.x] = sd[255];
}

__global__ void scan2_kernel(int* __restrict__ bsum, int nb) {
    __shared__ int sd[256];
    int t = threadIdx.x;
    int v = (t < nb) ? bsum[t] : 0;
    sd[t] = v;
    __syncthreads();
    for (int s = 1; s < 256; s <<= 1) {
        int u = (t >= s) ? sd[t - s] : 0;
        __syncthreads();
        sd[t] += u;
        __syncthreads();
    }
    if (t < nb) bsum[t] = sd[t] - v;   // exclusive
}

__global__ void scan3_kernel(int* __restrict__ off, const int* __restrict__ bsum,
                             int* __restrict__ cursor) {
    int i = blockIdx.x * 256 + threadIdx.x;
    if (i < NN) {
        int o = off[i] + bsum[blockIdx.x];
        off[i] = o;
        cursor[i] = o;
    }
    if (i == 0) off[NN] = NEDG;
}

__global__ void inv_kernel(const int* __restrict__ cnt, float* __restrict__ inv) {
    int n = blockIdx.x * blockDim.x + threadIdx.x;
    if (n < NN) inv[n] = 1.0f / (float)max(cnt[n], 1);
}

// EDG[slot] = src(17b) << 13 | ty(3b) << 10 | pos(10b), grouped by target via cursor
__global__ void fill_kernel(const int* __restrict__ el, const int* __restrict__ pl,
                            int* __restrict__ cursor, int* __restrict__ edg) {
    int idx = blockIdx.x * blockDim.x + threadIdx.x;
    if (idx >= NEDG) return;
    int ty = idx / EE, e = idx - ty * EE;
    int s, tg;
    if (ty < 3) {
        int2 pr = reinterpret_cast<const int2*>(el)[ty * EE + e];
        s = pr.x; tg = pr.y;
    } else {
        int2 pr = reinterpret_cast<const int2*>(el)[(ty - 3) * EE + e];
        s = pr.y; tg = pr.x;
    }
    int p = pl[(ty % 3) * EE + e];
    p = min(max(p, 0), PMX - 1);
    int slot = atomicAdd(&cursor[tg], 1);
    edg[slot] = (s << 13) | (ty << 10) | p;
}

// chunks[ty][n][j] (bf16) for all 6 ty: chunk = h @ msg_W[:, ty*H:(ty+1)*H] + msg_b[ty*H:]
// M=128 tile, 4 waves each owning 32 rows (2 row-frags), all 13 col-frags.
__global__ __launch_bounds__(256, 2) void prop_fused(
    const float* __restrict__ A, const unsigned short* __restrict__ BPp,
    const float* __restrict__ msg_b,
    unsigned short* __restrict__ CH0, unsigned short* __restrict__ CH45) {
    __shared__ unsigned short a_lds[128 * LDA];
    const int t = threadIdx.x;
    const int w = t >> 6;
    const int l = t & 63;
    const int lm = l & 15, lh = l >> 4;
    const int base = blockIdx.x * 128;

    for (int idx = t; idx < 128 * 101; idx += 256) {
        int row = idx / 101;
        int c = idx - row * 101;
        int gn = base + row;
        float2 v = make_float2(0.f, 0.f);
        if (gn < NN) v = *reinterpret_cast<const float2*>(&A[(size_t)gn * HH + c * 2]);
        ushort2 bv; bv.x = f2bf(v.x); bv.y = f2bf(v.y);
        *reinterpret_cast<ushort2*>(&a_lds[row * LDA + c * 2]) = bv;
    }
    for (int idx = t; idx < 128 * 11; idx += 256) {
        int row = idx / 11;
        int c = idx - row * 11;
        ushort2 z; z.x = 0; z.y = 0;
        *reinterpret_cast<ushort2*>(&a_lds[row * LDA + HH + c * 2]) = z;
    }
    __syncthreads();

#pragma unroll 1
    for (int ty = 0; ty < 6; ++ty) {
        const unsigned short* BP = BPp + (size_t)ty * PKSZ;
        v4f acc[2][13];
#pragma unroll
        for (int rf = 0; rf < 2; ++rf)
#pragma unroll
            for (int cf = 0; cf < 13; ++cf) acc[rf][cf] = (v4f){0.f, 0.f, 0.f, 0.f};

#pragma unroll 1
        for (int kt = 0; kt < NKT; ++kt) {
            short8 a0 = *reinterpret_cast<const short8*>(
                &a_lds[(w * 32 + lm) * LDA + kt * 32 + lh * 8]);
            short8 a1 = *reinterpret_cast<const short8*>(
                &a_lds[(w * 32 + 16 + lm) * LDA + kt * 32 + lh * 8]);
#pragma unroll
            for (int cf = 0; cf < 13; ++cf) {
                short8 b = *reinterpret_cast<const short8*>(
                    &BP[((size_t)(cf * NKT + kt) * 64 + l) * 8]);
                acc[0][cf] = __builtin_amdgcn_mfma_f32_16x16x32_bf16(a0, b, acc[0][cf], 0, 0, 0);
                acc[1][cf] = __builtin_amdgcn_mfma_f32_16x16x32_bf16(a1, b, acc[1][cf], 0, 0, 0);
            }
        }

        unsigned short* CH = (ty < 4) ? CH0 + (size_t)ty * NN * HH
                                      : CH45 + (size_t)(ty - 4) * NN * HH;
#pragma unroll
        for (int cf = 0; cf < 13; ++cf) {
            int col = cf * 16 + lm;
            if (col < HH) {
                float bb = msg_b[ty * HH + col];
#pragma unroll
                for (int rf = 0; rf < 2; ++rf) {
#pragma unroll
                    for (int r = 0; r < 4; ++r) {
                        int row = base + w * 32 + rf * 16 + lh * 4 + r;
                        if (row < NN) CH[(size_t)row * HH + col] = f2bf(acc[rf][cf][r] + bb);
                    }
                }
            }
        }
    }
}

// one wave per target node: MSG[n] = inv[n] * sum_edges chunk[ty][src] * gate[pos]
__global__ void agg_kernel(const unsigned short* __restrict__ CH0,
                           const unsigned short* __restrict__ CH45,
                           const int* __restrict__ off, const int* __restrict__ edg,
                           const unsigned short* __restrict__ gate,
                           const float* __restrict__ inv, float* __restrict__ msg) {
    int n = blockIdx.x * 4 + (threadIdx.x >> 6);
    if (n >= NN) return;
    int lane = threadIdx.x & 63;
    int s0 = off[n], s1 = off[n + 1];
    int j0 = lane, j1 = lane + 64, j2 = lane + 128, j3 = lane + 192;
    float a0 = 0.f, a1 = 0.f, a2 = 0.f, a3 = 0.f;
    for (int i = s0; i < s1; ++i) {
        int rec = edg[i];
        int src = rec >> 13;
        int ty = (rec >> 10) & 7;
        int p = rec & 1023;
        const unsigned short* cr =
            ((ty < 4) ? CH0 + (size_t)ty * NN * HH : CH45 + (size_t)(ty - 4) * NN * HH)
            + (size_t)src * HH;
        const unsigned short* gr = gate + (size_t)p * HH;
        a0 += bf2f(cr[j0]) * bf2f(gr[j0]);
        a1 += bf2f(cr[j1]) * bf2f(gr[j1]);
        a2 += bf2f(cr[j2]) * bf2f(gr[j2]);
        if (j3 < HH) a3 += bf2f(cr[j3]) * bf2f(gr[j3]);
    }
    float iv = inv[n];
    float* mr = msg + (size_t)n * HH;
    mr[j0] = a0 * iv; mr[j1] = a1 * iv; mr[j2] = a2 * iv;
    if (j3 < HH) mr[j3] = a3 * iv;
}

// Fused GRU: stages h & msg tiles (bf16), computes all 6 gate GEMM slices + elementwise,
// writes h in-place. M=64 tile; 4 waves = 2 row-groups(32 rows) x 2 col-groups(7|6 frags).
__global__ __launch_bounds__(256, 2) void gru_fused(
    float* __restrict__ h, const float* __restrict__ msg,
    const unsigned short* __restrict__ BPir, const unsigned short* __restrict__ BPiz,
    const unsigned short* __restrict__ BPin, const unsigned short* __restrict__ BPhr,
    const unsigned short* __restrict__ BPhz, const unsigned short* __restrict__ BPhn,
    const float* __restrict__ bih, const float* __restrict__ bhh) {
    __shared__ unsigned short hl[64 * LDA];
    __shared__ unsigned short ml[64 * LDA];
    const int t = threadIdx.x;
    const int w = t >> 6;
    const int l = t & 63;
    const int lm = l & 15, lh = l >> 4;
    const int rg = w >> 1, cg = w & 1;
    const int base = blockIdx.x * 64;
    const int ncf = cg ? 6 : 7;

    for (int idx = t; idx < 64 * 101; idx += 256) {
        int row = idx / 101;
        int c = idx - row * 101;
        int gn = base + row;
        float2 vh = make_float2(0.f, 0.f), vm = make_float2(0.f, 0.f);
        if (gn < NN) {
            vh = *reinterpret_cast<const float2*>(&h[(size_t)gn * HH + c * 2]);
            vm = *reinterpret_cast<const float2*>(&msg[(size_t)gn * HH + c * 2]);
        }
        ushort2 bh; bh.x = f2bf(vh.x); bh.y = f2bf(vh.y);
        ushort2 bm; bm.x = f2bf(vm.x); bm.y = f2bf(vm.y);
        *reinterpret_cast<ushort2*>(&hl[row * LDA + c * 2]) = bh;
        *reinterpret_cast<ushort2*>(&ml[row * LDA + c * 2]) = bm;
    }
    for (int idx = t; idx < 64 * 11; idx += 256) {
        int row = idx / 11;
        int c = idx - row * 11;
        ushort2 z; z.x = 0; z.y = 0;
        *reinterpret_cast<ushort2*>(&hl[row * LDA + HH + c * 2]) = z;
        *reinterpret_cast<ushort2*>(&ml[row * LDA + HH + c * 2]) = z;
    }
    __syncthreads();

    v4f aHN[2][7], aR[2][7], aIN[2][7];
#pragma unroll
    for (int rf = 0; rf < 2; ++rf)
#pragma unroll
        for (int ci = 0; ci < 7; ++ci) {
            aHN[rf][ci] = (v4f){0.f, 0.f, 0.f, 0.f};
            aR[rf][ci] = (v4f){0.f, 0.f, 0.f, 0.f};
            aIN[rf][ci] = (v4f){0.f, 0.f, 0.f, 0.f};
        }

    // pass 1: aHN = h @ Whh_n ; aR = msg @ Wih_r + h @ Whh_r ; aIN = msg @ Wih_n
#pragma unroll 1
    for (int kt = 0; kt < NKT; ++kt) {
        short8 ah0 = *reinterpret_cast<const short8*>(&hl[(rg * 32 + lm) * LDA + kt * 32 + lh * 8]);
        short8 ah1 = *reinterpret_cast<const short8*>(&hl[(rg * 32 + 16 + lm) * LDA + kt * 32 + lh * 8]);
        short8 am0 = *reinterpret_cast<const short8*>(&ml[(rg * 32 + lm) * LDA + kt * 32 + lh * 8]);
        short8 am1 = *reinterpret_cast<const short8*>(&ml[(rg * 32 + 16 + lm) * LDA + kt * 32 + lh * 8]);
#pragma unroll
        for (int ci = 0; ci < 7; ++ci) {
            if (ci < ncf) {
                int cf = cg * 7 + ci;
                size_t bo = ((size_t)(cf * NKT + kt) * 64 + l) * 8;
                short8 bhn = *reinterpret_cast<const short8*>(&BPhn[bo]);
                aHN[0][ci] = __builtin_amdgcn_mfma_f32_16x16x32_bf16(ah0, bhn, aHN[0][ci], 0, 0, 0);
                aHN[1][ci] = __builtin_amdgcn_mfma_f32_16x16x32_bf16(ah1, bhn, aHN[1][ci], 0, 0, 0);
                short8 bir = *reinterpret_cast<const short8*>(&BPir[bo]);
                aR[0][ci] = __builtin_amdgcn_mfma_f32_16x16x32_bf16(am0, bir, aR[0][ci], 0, 0, 0);
                aR[1][ci] = __builtin_amdgcn_mfma_f32_16x16x32_bf16(am1, bir, aR[1][ci], 0, 0, 0);
                short8 bhr = *reinterpret_cast<const short8*>(&BPhr[bo]);
                aR[0][ci] = __builtin_amdgcn_mfma_f32_16x16x32_bf16(ah0, bhr, aR[0][ci], 0, 0, 0);
                aR[1][ci] = __builtin_amdgcn_mfma_f32_16x16x32_bf16(ah1, bhr, aR[1][ci], 0, 0, 0);
                short8 bin = *reinterpret_cast<const short8*>(&BPin[bo]);
                aIN[0][ci] = __builtin_amdgcn_mfma_f32_16x16x32_bf16(am0, bin, aIN[0][ci], 0, 0, 0);
                aIN[1][ci] = __builtin_amdgcn_mfma_f32_16x16x32_bf16(am1, bin, aIN[1][ci], 0, 0, 0);
            }
        }
    }

    // n = tanh(inn + bih_n + r * (hn + bhh_n)), r = sig(sr + biases); store n into aIN
#pragma unroll
    for (int ci = 0; ci < 7; ++ci) {
        if (ci < ncf) {
            int col = (cg * 7 + ci) * 16 + lm;
            bool cok = col < HH;
            float br = cok ? (bih[col] + bhh[col]) : 0.f;
            float bn_i = cok ? bih[404 + col] : 0.f;
            float bn_h = cok ? bhh[404 + col] : 0.f;
#pragma unroll
            for (int rf = 0; rf < 2; ++rf) {
#pragma unroll
                for (int r = 0; r < 4; ++r) {
                    float rr = sigf(aR[rf][ci][r] + br);
                    aIN[rf][ci][r] = tanhf(aIN[rf][ci][r] + bn_i + rr * (aHN[rf][ci][r] + bn_h));
                }
            }
        }
    }

    // pass 2: aZ (reuse aHN) = msg @ Wih_z + h @ Whh_z
#pragma unroll
    for (int rf = 0; rf < 2; ++rf)
#pragma unroll
        for (int ci = 0; ci < 7; ++ci) aHN[rf][ci] = (v4f){0.f, 0.f, 0.f, 0.f};
#pragma unroll 1
    for (int kt = 0; kt < NKT; ++kt) {
        short8 ah0 = *reinterpret_cast<const short8*>(&hl[(rg * 32 + lm) * LDA + kt * 32 + lh * 8]);
        short8 ah1 = *reinterpret_cast<const short8*>(&hl[(rg * 32 + 16 + lm) * LDA + kt * 32 + lh * 8]);
        short8 am0 = *reinterpret_cast<const short8*>(&ml[(rg * 32 + lm) * LDA + kt * 32 + lh * 8]);
        short8 am1 = *reinterpret_cast<const short8*>(&ml[(rg * 32 + 16 + lm) * LDA + kt * 32 + lh * 8]);
#pragma unroll
        for (int ci = 0; ci < 7; ++ci) {
            if (ci < ncf) {
                int cf = cg * 7 + ci;
                size_t bo = ((size_t)(cf * NKT + kt) * 64 + l) * 8;
                short8 biz = *reinterpret_cast<const short8*>(&BPiz[bo]);
                aHN[0][ci] = __builtin_amdgcn_mfma_f32_16x16x32_bf16(am0, biz, aHN[0][ci], 0, 0, 0);
                aHN[1][ci] = __builtin_amdgcn_mfma_f32_16x16x32_bf16(am1, biz, aHN[1][ci], 0, 0, 0);
                short8 bhz = *reinterpret_cast<const short8*>(&BPhz[bo]);
                aHN[0][ci] = __builtin_amdgcn_mfma_f32_16x16x32_bf16(ah0, bhz, aHN[0][ci], 0, 0, 0);
                aHN[1][ci] = __builtin_amdgcn_mfma_f32_16x16x32_bf16(ah1, bhz, aHN[1][ci], 0, 0, 0);
            }
        }
    }

    // h' = (1-z)*n + z*h  (h re-read f32 from global for precision)
#pragma unroll
    for (int ci = 0; ci < 7; ++ci) {
        if (ci < ncf) {
            int col = (cg * 7 + ci) * 16 + lm;
            if (col < HH) {
                float bz = bih[202 + col] + bhh[202 + col];
#pragma unroll
                for (int rf = 0; rf < 2; ++rf) {
#pragma unroll
                    for (int r = 0; r < 4; ++r) {
                        int row = base + rg * 32 + rf * 16 + lh * 4 + r;
                        if (row < NN) {
                            float z = sigf(aHN[rf][ci][r] + bz);
                            float hv = h[(size_t)row * HH + col];
                            h[(size_t)row * HH + col] =
                                (1.0f - z) * aIN[rf][ci][r] + z * hv;
                        }
                    }
                }
            }
        }
    }
}

extern "C" void kernel_launch(void* const* d_in, const int* in_sizes, int n_in,
                              void* d_out, int out_size, void* d_ws, size_t ws_size,
                              hipStream_t stream) {
    const float* node_states = (const float*)d_in[0];
    const int*   el          = (const int*)d_in[1];
    const int*   pl          = (const int*)d_in[2];
    const float* msg_W       = (const float*)d_in[3];
    const float* msg_b       = (const float*)d_in[4];
    const float* pos_W       = (const float*)d_in[5];
    const float* pos_b       = (const float*)d_in[6];
    const float* gWih        = (const float*)d_in[7];
    const float* gWhh        = (const float*)d_in[8];
    const float* gbih        = (const float*)d_in[9];
    const float* gbhh        = (const float*)d_in[10];

    float* out  = (float*)d_out;
    float* h    = out;                               // [N,H] final h
    float* out2 = out + (size_t)NN * HH;             // chunks ty=4,5 during steps; node_states at end

    unsigned short* CH0  = (unsigned short*)d_ws;                    // 4 slabs bf16 [N,H]
    unsigned short* CH45 = (unsigned short*)out2;                    // 2 slabs bf16 [N,H]
    float* MSG  = (float*)(CH0 + (size_t)4 * NN * HH);               // [N,H] f32
    unsigned short* GATE = (unsigned short*)(MSG + (size_t)NN * HH); // [1024,H] bf16
    float* INV  = (float*)(GATE + (size_t)PMX * HH);                 // [N]
    int* CNT    = (int*)(INV + NN);                                  // [N]
    int* OFF    = CNT + NN;                                          // [N+4]
    int* CUR    = OFF + NN + 4;                                      // [N]
    int* BS     = CUR + NN;                                          // [256]
    int* EDG    = BS + 256;                                          // [600000]
    unsigned short* BPA = (unsigned short*)(EDG + NEDG);             // 12 packs
    unsigned short* BPp  = BPA;
    unsigned short* BPir = BPA + (size_t)6 * PKSZ;
    unsigned short* BPiz = BPA + (size_t)7 * PKSZ;
    unsigned short* BPin = BPA + (size_t)8 * PKSZ;
    unsigned short* BPhr = BPA + (size_t)9 * PKSZ;
    unsigned short* BPhz = BPA + (size_t)10 * PKSZ;
    unsigned short* BPhn = BPA + (size_t)11 * PKSZ;

    const size_t NH = (size_t)NN * HH;
    hipMemcpyAsync(h, node_states, NH * sizeof(float), hipMemcpyDeviceToDevice, stream);
    hipMemsetAsync(CNT, 0, NN * sizeof(int), stream);
    gate_kernel<<<PMX, 256, 0, stream>>>(pos_W, pos_b, GATE);
    const int pkb = (PKSZ + 255) / 256;
    for (int ty = 0; ty < 6; ++ty)
        pack_kernel<<<pkb, 256, 0, stream>>>(msg_W, 1212, 0, ty * HH, 0, BPp + (size_t)ty * PKSZ);
    pack_kernel<<<pkb, 256, 0, stream>>>(gWih, 0, 0,   0, 1, BPir);
    pack_kernel<<<pkb, 256, 0, stream>>>(gWih, 0, 202, 0, 1, BPiz);
    pack_kernel<<<pkb, 256, 0, stream>>>(gWih, 0, 404, 0, 1, BPin);
    pack_kernel<<<pkb, 256, 0, stream>>>(gWhh, 0, 0,   0, 1, BPhr);
    pack_kernel<<<pkb, 256, 0, stream>>>(gWhh, 0, 202, 0, 1, BPhz);
    pack_kernel<<<pkb, 256, 0, stream>>>(gWhh, 0, 404, 0, 1, BPhn);

    const int nsb = (NN + 255) / 256;    // 196
    count_kernel<<<(NEDG + 255) / 256, 256, 0, stream>>>(el, CNT);
    scan1_kernel<<<nsb, 256, 0, stream>>>(CNT, OFF, BS);
    scan2_kernel<<<1, 256, 0, stream>>>(BS, nsb);
    scan3_kernel<<<nsb, 256, 0, stream>>>(OFF, BS, CUR);
    inv_kernel<<<nsb, 256, 0, stream>>>(CNT, INV);
    fill_kernel<<<(NEDG + 255) / 256, 256, 0, stream>>>(el, pl, CUR, EDG);

    for (int step = 0; step < 2; ++step) {
        prop_fused<<<(NN + 127) / 128, 256, 0, stream>>>(h, BPp, msg_b, CH0, CH45);
        agg_kernel<<<(NN + 3) / 4, 256, 0, stream>>>(CH0, CH45, OFF, EDG, GATE, INV, MSG);
        gru_fused<<<(NN + 63) / 64, 256, 0, stream>>>(h, MSG, BPir, BPiz, BPin,
                                                      BPhr, BPhz, BPhn, gbih, gbhh);
    }
    hipMemcpyAsync(out2, node_states, NH * sizeof(float), hipMemcpyDeviceToDevice, stream);
}

// Round 4
// 1081.647 us; speedup vs baseline: 3.9758x; 1.0419x over previous
//
#include <hip/hip_runtime.h>

#define NN 50000
#define HH 202
#define EE 100000
#define PMX 1024
#define NKT 7          // k-steps of 32 (K padded to 224)
#define LDA 232        // LDS A row stride in ushorts
#define PKSZ (13 * NKT * 64 * 8)   // ushorts per B pack = 46592
#define NEDG (6 * EE)

typedef __attribute__((ext_vector_type(8))) short short8;
typedef __attribute__((ext_vector_type(4))) float v4f;

__device__ __forceinline__ float sigf(float x) { return 1.0f / (1.0f + expf(-x)); }

__device__ __forceinline__ unsigned short f2bf(float x) {
    unsigned int u = __float_as_uint(x);
    unsigned int r = (u + 0x7fffu + ((u >> 16) & 1u)) >> 16;
    return (unsigned short)r;
}
__device__ __forceinline__ float bf2f(unsigned short u) {
    return __uint_as_float(((unsigned int)u) << 16);
}

// gate[p][j] = bf16( 2*sigmoid(sum_k pt[p][k]*pos_W[k][j] + pos_b[j]) )
__global__ void gate_kernel(const float* __restrict__ pos_W, const float* __restrict__ pos_b,
                            unsigned short* __restrict__ gate) {
    int p = blockIdx.x;
    __shared__ float pt[HH];
    int t = threadIdx.x;
    if (t < HH) {
        float v;
        if (t < 101) {
            float invf = expf(-(2.0f * t / 202.0f) * 9.210340371976184f); // ln(10000)
            v = sinf((float)p * invf);
        } else {
            int k = t - 101;
            float invf = expf(-(2.0f * k / 202.0f) * 9.210340371976184f);
            v = cosf((float)p * invf);
        }
        pt[t] = v;
    }
    __syncthreads();
    for (int j = t; j < HH; j += blockDim.x) {
        float acc = pos_b[j];
        for (int k = 0; k < HH; ++k) acc += pt[k] * pos_W[k * HH + j];
        gate[p * HH + j] = f2bf(2.0f * sigf(acc));
    }
}

// Pack B into MFMA fragment order, f32 -> bf16.
// BP[((cf*NKT + kt)*64 + l)*8 + jj] = B[k][j], k = kt*32 + (l>>4)*8 + jj, j = cf*16 + (l&15)
// mode 0: B[k][j] = S[k*ldb + col0 + j]          (msg_W row-major)
// mode 1: B[k][j] = S[(row0 + j)*HH + k]         (GRU W [606][202], transposed use)
__global__ void pack_kernel(const float* __restrict__ S, int ldb, int row0, int col0, int mode,
                            unsigned short* __restrict__ BP) {
    int idx = blockIdx.x * blockDim.x + threadIdx.x;
    if (idx >= PKSZ) return;
    int jj = idx & 7;
    int l = (idx >> 3) & 63;
    int r2 = idx >> 9;             // cf*NKT + kt
    int cf = r2 / NKT, kt = r2 - cf * NKT;
    int k = kt * 32 + ((l >> 4) << 3) + jj;
    int j = cf * 16 + (l & 15);
    float v = 0.0f;
    if (k < HH && j < HH)
        v = mode ? S[(size_t)(row0 + j) * HH + k] : S[(size_t)k * ldb + col0 + j];
    BP[idx] = f2bf(v);
}

__global__ void count_kernel(const int* __restrict__ el, int* __restrict__ cnt) {
    int idx = blockIdx.x * blockDim.x + threadIdx.x;
    if (idx >= NEDG) return;
    int ty = idx / EE, e = idx - ty * EE;
    int2 pr = (ty < 3) ? reinterpret_cast<const int2*>(el)[ty * EE + e]
                       : reinterpret_cast<const int2*>(el)[(ty - 3) * EE + e];
    int tg = (ty < 3) ? pr.y : pr.x;
    atomicAdd(&cnt[tg], 1);
}

__global__ void scan1_kernel(const int* __restrict__ cnt, int* __restrict__ off,
                             int* __restrict__ bsum) {
    __shared__ int sd[256];
    int t = threadIdx.x, i = blockIdx.x * 256 + t;
    int v = (i < NN) ? cnt[i] : 0;
    sd[t] = v;
    __syncthreads();
    for (int s = 1; s < 256; s <<= 1) {
        int u = (t >= s) ? sd[t - s] : 0;
        __syncthreads();
        sd[t] += u;
        __syncthreads();
    }
    if (i < NN) off[i] = sd[t] - v;
    if (t == 255) bsum[blockIdx.x] = sd[255];
}

__global__ void scan2_kernel(int* __restrict__ bsum, int nb) {
    __shared__ int sd[256];
    int t = threadIdx.x;
    int v = (t < nb) ? bsum[t] : 0;
    sd[t] = v;
    __syncthreads();
    for (int s = 1; s < 256; s <<= 1) {
        int u = (t >= s) ? sd[t - s] : 0;
        __syncthreads();
        sd[t] += u;
        __syncthreads();
    }
    if (t < nb) bsum[t] = sd[t] - v;   // exclusive
}

__global__ void scan3_kernel(int* __restrict__ off, const int* __restrict__ bsum,
                             int* __restrict__ cursor) {
    int i = blockIdx.x * 256 + threadIdx.x;
    if (i < NN) {
        int o = off[i] + bsum[blockIdx.x];
        off[i] = o;
        cursor[i] = o;
    }
    if (i == 0) off[NN] = NEDG;
}

__global__ void inv_kernel(const int* __restrict__ cnt, float* __restrict__ inv) {
    int n = blockIdx.x * blockDim.x + threadIdx.x;
    if (n < NN) inv[n] = 1.0f / (float)max(cnt[n], 1);
}

// EDG[slot] = src(17b) << 13 | ty(3b) << 10 | pos(10b), grouped by target via cursor
__global__ void fill_kernel(const int* __restrict__ el, const int* __restrict__ pl,
                            int* __restrict__ cursor, int* __restrict__ edg) {
    int idx = blockIdx.x * blockDim.x + threadIdx.x;
    if (idx >= NEDG) return;
    int ty = idx / EE, e = idx - ty * EE;
    int s, tg;
    if (ty < 3) {
        int2 pr = reinterpret_cast<const int2*>(el)[ty * EE + e];
        s = pr.x; tg = pr.y;
    } else {
        int2 pr = reinterpret_cast<const int2*>(el)[(ty - 3) * EE + e];
        s = pr.y; tg = pr.x;
    }
    int p = pl[(ty % 3) * EE + e];
    p = min(max(p, 0), PMX - 1);
    int slot = atomicAdd(&cursor[tg], 1);
    edg[slot] = (s << 13) | (ty << 10) | p;
}

// chunks[ty][n][j] (bf16) for all 6 ty. M=64 tile, 4 waves x 1 row-frag x 13 col-frags.
__global__ __launch_bounds__(256, 4) void prop_fused(
    const float* __restrict__ A, const unsigned short* __restrict__ BPp,
    const float* __restrict__ msg_b,
    unsigned short* __restrict__ CH0, unsigned short* __restrict__ CH45) {
    __shared__ unsigned short a_lds[64 * LDA];
    const int t = threadIdx.x;
    const int w = t >> 6;
    const int l = t & 63;
    const int lm = l & 15, lh = l >> 4;
    const int base = blockIdx.x * 64;

    for (int idx = t; idx < 64 * 101; idx += 256) {
        int row = idx / 101;
        int c = idx - row * 101;
        int gn = base + row;
        float2 v = make_float2(0.f, 0.f);
        if (gn < NN) v = *reinterpret_cast<const float2*>(&A[(size_t)gn * HH + c * 2]);
        ushort2 bv; bv.x = f2bf(v.x); bv.y = f2bf(v.y);
        *reinterpret_cast<ushort2*>(&a_lds[row * LDA + c * 2]) = bv;
    }
    for (int idx = t; idx < 64 * 11; idx += 256) {
        int row = idx / 11;
        int c = idx - row * 11;
        ushort2 z; z.x = 0; z.y = 0;
        *reinterpret_cast<ushort2*>(&a_lds[row * LDA + HH + c * 2]) = z;
    }
    __syncthreads();

#pragma unroll 1
    for (int ty = 0; ty < 6; ++ty) {
        const unsigned short* BP = BPp + (size_t)ty * PKSZ;
        v4f acc[13];
#pragma unroll
        for (int cf = 0; cf < 13; ++cf) acc[cf] = (v4f){0.f, 0.f, 0.f, 0.f};

#pragma unroll 2
        for (int kt = 0; kt < NKT; ++kt) {
            short8 a = *reinterpret_cast<const short8*>(
                &a_lds[(w * 16 + lm) * LDA + kt * 32 + lh * 8]);
#pragma unroll
            for (int cf = 0; cf < 13; ++cf) {
                short8 b = *reinterpret_cast<const short8*>(
                    &BP[((size_t)(cf * NKT + kt) * 64 + l) * 8]);
                acc[cf] = __builtin_amdgcn_mfma_f32_16x16x32_bf16(a, b, acc[cf], 0, 0, 0);
            }
        }

        unsigned short* CH = (ty < 4) ? CH0 + (size_t)ty * NN * HH
                                      : CH45 + (size_t)(ty - 4) * NN * HH;
#pragma unroll
        for (int cf = 0; cf < 13; ++cf) {
            int col = cf * 16 + lm;
            if (col < HH) {
                float bb = msg_b[ty * HH + col];
#pragma unroll
                for (int r = 0; r < 4; ++r) {
                    int row = base + w * 16 + lh * 4 + r;
                    if (row < NN) CH[(size_t)row * HH + col] = f2bf(acc[cf][r] + bb);
                }
            }
        }
    }
}

// one wave per target node: MSG[n] = inv[n] * sum_edges chunk[ty][src] * gate[pos]
__global__ void agg_kernel(const unsigned short* __restrict__ CH0,
                           const unsigned short* __restrict__ CH45,
                           const int* __restrict__ off, const int* __restrict__ edg,
                           const unsigned short* __restrict__ gate,
                           const float* __restrict__ inv, float* __restrict__ msg) {
    int n = blockIdx.x * 4 + (threadIdx.x >> 6);
    if (n >= NN) return;
    int lane = threadIdx.x & 63;
    int s0 = off[n], s1 = off[n + 1];
    int j0 = lane, j1 = lane + 64, j2 = lane + 128, j3 = lane + 192;
    float a0 = 0.f, a1 = 0.f, a2 = 0.f, a3 = 0.f;
    for (int i = s0; i < s1; ++i) {
        int rec = edg[i];
        int src = rec >> 13;
        int ty = (rec >> 10) & 7;
        int p = rec & 1023;
        const unsigned short* cr =
            ((ty < 4) ? CH0 + (size_t)ty * NN * HH : CH45 + (size_t)(ty - 4) * NN * HH)
            + (size_t)src * HH;
        const unsigned short* gr = gate + (size_t)p * HH;
        a0 += bf2f(cr[j0]) * bf2f(gr[j0]);
        a1 += bf2f(cr[j1]) * bf2f(gr[j1]);
        a2 += bf2f(cr[j2]) * bf2f(gr[j2]);
        if (j3 < HH) a3 += bf2f(cr[j3]) * bf2f(gr[j3]);
    }
    float iv = inv[n];
    float* mr = msg + (size_t)n * HH;
    mr[j0] = a0 * iv; mr[j1] = a1 * iv; mr[j2] = a2 * iv;
    if (j3 < HH) mr[j3] = a3 * iv;
}

// Fused GRU: M=32 tile; 4 waves = 2 row-frags x 2 col-groups (7|6 frags).
__global__ __launch_bounds__(256, 4) void gru_fused(
    float* __restrict__ h, const float* __restrict__ msg,
    const unsigned short* __restrict__ BPir, const unsigned short* __restrict__ BPiz,
    const unsigned short* __restrict__ BPin, const unsigned short* __restrict__ BPhr,
    const unsigned short* __restrict__ BPhz, const unsigned short* __restrict__ BPhn,
    const float* __restrict__ bih, const float* __restrict__ bhh) {
    __shared__ unsigned short hl[32 * LDA];
    __shared__ unsigned short ml[32 * LDA];
    const int t = threadIdx.x;
    const int w = t >> 6;
    const int l = t & 63;
    const int lm = l & 15, lh = l >> 4;
    const int rg = w >> 1, cg = w & 1;
    const int base = blockIdx.x * 32;
    const int ncf = cg ? 6 : 7;

    for (int idx = t; idx < 32 * 101; idx += 256) {
        int row = idx / 101;
        int c = idx - row * 101;
        int gn = base + row;
        float2 vh = make_float2(0.f, 0.f), vm = make_float2(0.f, 0.f);
        if (gn < NN) {
            vh = *reinterpret_cast<const float2*>(&h[(size_t)gn * HH + c * 2]);
            vm = *reinterpret_cast<const float2*>(&msg[(size_t)gn * HH + c * 2]);
        }
        ushort2 bh; bh.x = f2bf(vh.x); bh.y = f2bf(vh.y);
        ushort2 bm; bm.x = f2bf(vm.x); bm.y = f2bf(vm.y);
        *reinterpret_cast<ushort2*>(&hl[row * LDA + c * 2]) = bh;
        *reinterpret_cast<ushort2*>(&ml[row * LDA + c * 2]) = bm;
    }
    for (int idx = t; idx < 32 * 11; idx += 256) {
        int row = idx / 11;
        int c = idx - row * 11;
        ushort2 z; z.x = 0; z.y = 0;
        *reinterpret_cast<ushort2*>(&hl[row * LDA + HH + c * 2]) = z;
        *reinterpret_cast<ushort2*>(&ml[row * LDA + HH + c * 2]) = z;
    }
    __syncthreads();

    v4f aHN[7], aR[7], aIN[7];
#pragma unroll
    for (int ci = 0; ci < 7; ++ci) {
        aHN[ci] = (v4f){0.f, 0.f, 0.f, 0.f};
        aR[ci] = (v4f){0.f, 0.f, 0.f, 0.f};
        aIN[ci] = (v4f){0.f, 0.f, 0.f, 0.f};
    }

    // pass 1: aHN = h @ Whh_n ; aR = msg @ Wih_r + h @ Whh_r ; aIN = msg @ Wih_n
#pragma unroll 1
    for (int kt = 0; kt < NKT; ++kt) {
        short8 ah = *reinterpret_cast<const short8*>(&hl[(rg * 16 + lm) * LDA + kt * 32 + lh * 8]);
        short8 am = *reinterpret_cast<const short8*>(&ml[(rg * 16 + lm) * LDA + kt * 32 + lh * 8]);
#pragma unroll
        for (int ci = 0; ci < 7; ++ci) {
            if (ci < ncf) {
                int cf = cg * 7 + ci;
                size_t bo = ((size_t)(cf * NKT + kt) * 64 + l) * 8;
                short8 bhn = *reinterpret_cast<const short8*>(&BPhn[bo]);
                aHN[ci] = __builtin_amdgcn_mfma_f32_16x16x32_bf16(ah, bhn, aHN[ci], 0, 0, 0);
                short8 bir = *reinterpret_cast<const short8*>(&BPir[bo]);
                aR[ci] = __builtin_amdgcn_mfma_f32_16x16x32_bf16(am, bir, aR[ci], 0, 0, 0);
                short8 bhr = *reinterpret_cast<const short8*>(&BPhr[bo]);
                aR[ci] = __builtin_amdgcn_mfma_f32_16x16x32_bf16(ah, bhr, aR[ci], 0, 0, 0);
                short8 bin = *reinterpret_cast<const short8*>(&BPin[bo]);
                aIN[ci] = __builtin_amdgcn_mfma_f32_16x16x32_bf16(am, bin, aIN[ci], 0, 0, 0);
            }
        }
    }

    // n = tanh(inn + bih_n + r * (hn + bhh_n)), r = sig(sr + biases); store n into aIN
#pragma unroll
    for (int ci = 0; ci < 7; ++ci) {
        if (ci < ncf) {
            int col = (cg * 7 + ci) * 16 + lm;
            bool cok = col < HH;
            float br = cok ? (bih[col] + bhh[col]) : 0.f;
            float bn_i = cok ? bih[404 + col] : 0.f;
            float bn_h = cok ? bhh[404 + col] : 0.f;
#pragma unroll
            for (int r = 0; r < 4; ++r) {
                float rr = sigf(aR[ci][r] + br);
                aIN[ci][r] = tanhf(aIN[ci][r] + bn_i + rr * (aHN[ci][r] + bn_h));
            }
        }
    }

    // pass 2: aZ (reuse aHN) = msg @ Wih_z + h @ Whh_z
#pragma unroll
    for (int ci = 0; ci < 7; ++ci) aHN[ci] = (v4f){0.f, 0.f, 0.f, 0.f};
#pragma unroll 1
    for (int kt = 0; kt < NKT; ++kt) {
        short8 ah = *reinterpret_cast<const short8*>(&hl[(rg * 16 + lm) * LDA + kt * 32 + lh * 8]);
        short8 am = *reinterpret_cast<const short8*>(&ml[(rg * 16 + lm) * LDA + kt * 32 + lh * 8]);
#pragma unroll
        for (int ci = 0; ci < 7; ++ci) {
            if (ci < ncf) {
                int cf = cg * 7 + ci;
                size_t bo = ((size_t)(cf * NKT + kt) * 64 + l) * 8;
                short8 biz = *reinterpret_cast<const short8*>(&BPiz[bo]);
                aHN[ci] = __builtin_amdgcn_mfma_f32_16x16x32_bf16(am, biz, aHN[ci], 0, 0, 0);
                short8 bhz = *reinterpret_cast<const short8*>(&BPhz[bo]);
                aHN[ci] = __builtin_amdgcn_mfma_f32_16x16x32_bf16(ah, bhz, aHN[ci], 0, 0, 0);
            }
        }
    }

    // h' = (1-z)*n + z*h  (h re-read f32 from global for precision)
#pragma unroll
    for (int ci = 0; ci < 7; ++ci) {
        if (ci < ncf) {
            int col = (cg * 7 + ci) * 16 + lm;
            if (col < HH) {
                float bz = bih[202 + col] + bhh[202 + col];
#pragma unroll
                for (int r = 0; r < 4; ++r) {
                    int row = base + rg * 16 + lh * 4 + r;
                    if (row < NN) {
                        float z = sigf(aHN[ci][r] + bz);
                        float hv = h[(size_t)row * HH + col];
                        h[(size_t)row * HH + col] = (1.0f - z) * aIN[ci][r] + z * hv;
                    }
                }
            }
        }
    }
}

extern "C" void kernel_launch(void* const* d_in, const int* in_sizes, int n_in,
                              void* d_out, int out_size, void* d_ws, size_t ws_size,
                              hipStream_t stream) {
    const float* node_states = (const float*)d_in[0];
    const int*   el          = (const int*)d_in[1];
    const int*   pl          = (const int*)d_in[2];
    const float* msg_W       = (const float*)d_in[3];
    const float* msg_b       = (const float*)d_in[4];
    const float* pos_W       = (const float*)d_in[5];
    const float* pos_b       = (const float*)d_in[6];
    const float* gWih        = (const float*)d_in[7];
    const float* gWhh        = (const float*)d_in[8];
    const float* gbih        = (const float*)d_in[9];
    const float* gbhh        = (const float*)d_in[10];

    float* out  = (float*)d_out;
    float* h    = out;                               // [N,H] final h
    float* out2 = out + (size_t)NN * HH;             // chunks ty=4,5 during steps; node_states at end

    unsigned short* CH0  = (unsigned short*)d_ws;                    // 4 slabs bf16 [N,H]
    unsigned short* CH45 = (unsigned short*)out2;                    // 2 slabs bf16 [N,H]
    float* MSG  = (float*)(CH0 + (size_t)4 * NN * HH);               // [N,H] f32
    unsigned short* GATE = (unsigned short*)(MSG + (size_t)NN * HH); // [1024,H] bf16
    float* INV  = (float*)(GATE + (size_t)PMX * HH);                 // [N]
    int* CNT    = (int*)(INV + NN);                                  // [N]
    int* OFF    = CNT + NN;                                          // [N+4]
    int* CUR    = OFF + NN + 4;                                      // [N]
    int* BS     = CUR + NN;                                          // [256]
    int* EDG    = BS + 256;                                          // [600000]
    unsigned short* BPA = (unsigned short*)(EDG + NEDG);             // 12 packs
    unsigned short* BPp  = BPA;
    unsigned short* BPir = BPA + (size_t)6 * PKSZ;
    unsigned short* BPiz = BPA + (size_t)7 * PKSZ;
    unsigned short* BPin = BPA + (size_t)8 * PKSZ;
    unsigned short* BPhr = BPA + (size_t)9 * PKSZ;
    unsigned short* BPhz = BPA + (size_t)10 * PKSZ;
    unsigned short* BPhn = BPA + (size_t)11 * PKSZ;

    const size_t NH = (size_t)NN * HH;
    hipMemcpyAsync(h, node_states, NH * sizeof(float), hipMemcpyDeviceToDevice, stream);
    hipMemsetAsync(CNT, 0, NN * sizeof(int), stream);
    gate_kernel<<<PMX, 256, 0, stream>>>(pos_W, pos_b, GATE);
    const int pkb = (PKSZ + 255) / 256;
    for (int ty = 0; ty < 6; ++ty)
        pack_kernel<<<pkb, 256, 0, stream>>>(msg_W, 1212, 0, ty * HH, 0, BPp + (size_t)ty * PKSZ);
    pack_kernel<<<pkb, 256, 0, stream>>>(gWih, 0, 0,   0, 1, BPir);
    pack_kernel<<<pkb, 256, 0, stream>>>(gWih, 0, 202, 0, 1, BPiz);
    pack_kernel<<<pkb, 256, 0, stream>>>(gWih, 0, 404, 0, 1, BPin);
    pack_kernel<<<pkb, 256, 0, stream>>>(gWhh, 0, 0,   0, 1, BPhr);
    pack_kernel<<<pkb, 256, 0, stream>>>(gWhh, 0, 202, 0, 1, BPhz);
    pack_kernel<<<pkb, 256, 0, stream>>>(gWhh, 0, 404, 0, 1, BPhn);

    const int nsb = (NN + 255) / 256;    // 196
    count_kernel<<<(NEDG + 255) / 256, 256, 0, stream>>>(el, CNT);
    scan1_kernel<<<nsb, 256, 0, stream>>>(CNT, OFF, BS);
    scan2_kernel<<<1, 256, 0, stream>>>(BS, nsb);
    scan3_kernel<<<nsb, 256, 0, stream>>>(OFF, BS, CUR);
    inv_kernel<<<nsb, 256, 0, stream>>>(CNT, INV);
    fill_kernel<<<(NEDG + 255) / 256, 256, 0, stream>>>(el, pl, CUR, EDG);

    for (int step = 0; step < 2; ++step) {
        prop_fused<<<(NN + 63) / 64, 256, 0, stream>>>(h, BPp, msg_b, CH0, CH45);
        agg_kernel<<<(NN + 3) / 4, 256, 0, stream>>>(CH0, CH45, OFF, EDG, GATE, INV, MSG);
        gru_fused<<<(NN + 31) / 32, 256, 0, stream>>>(h, MSG, BPir, BPiz, BPin,
                                                      BPhr, BPhz, BPhn, gbih, gbhh);
    }
    hipMemcpyAsync(out2, node_states, NH * sizeof(float), hipMemcpyDeviceToDevice, stream);
}

// Round 5
// 870.670 us; speedup vs baseline: 4.9392x; 1.2423x over previous
//
#include <hip/hip_runtime.h>

#define NN 50000
#define HH 202
#define EE 100000
#define PMX 1024
#define NKT 7          // k-steps of 32 (K padded to 224)
#define LDA 232        // LDS A row stride in ushorts (bank-spread verified)
#define PKSZ (13 * NKT * 64 * 8)   // ushorts per B pack = 46592
#define NEDG (6 * EE)

typedef __attribute__((ext_vector_type(8))) short short8;
typedef __attribute__((ext_vector_type(4))) float v4f;

__device__ __forceinline__ float sigf(float x) { return 1.0f / (1.0f + expf(-x)); }

__device__ __forceinline__ unsigned short f2bf(float x) {
    unsigned int u = __float_as_uint(x);
    unsigned int r = (u + 0x7fffu + ((u >> 16) & 1u)) >> 16;
    return (unsigned short)r;
}
__device__ __forceinline__ float bf2f(unsigned short u) {
    return __uint_as_float(((unsigned int)u) << 16);
}

// gate[p][j] = bf16( 2*sigmoid(sum_k pt[p][k]*pos_W[k][j] + pos_b[j]) )
__global__ void gate_kernel(const float* __restrict__ pos_W, const float* __restrict__ pos_b,
                            unsigned short* __restrict__ gate) {
    int p = blockIdx.x;
    __shared__ float pt[HH];
    int t = threadIdx.x;
    if (t < HH) {
        float v;
        if (t < 101) {
            float invf = expf(-(2.0f * t / 202.0f) * 9.210340371976184f); // ln(10000)
            v = sinf((float)p * invf);
        } else {
            int k = t - 101;
            float invf = expf(-(2.0f * k / 202.0f) * 9.210340371976184f);
            v = cosf((float)p * invf);
        }
        pt[t] = v;
    }
    __syncthreads();
    for (int j = t; j < HH; j += blockDim.x) {
        float acc = pos_b[j];
        for (int k = 0; k < HH; ++k) acc += pt[k] * pos_W[k * HH + j];
        gate[p * HH + j] = f2bf(2.0f * sigf(acc));
    }
}

// Pack B into MFMA fragment order, f32 -> bf16.
// BP[((cf*NKT + kt)*64 + l)*8 + jj] = B[k][j], k = kt*32 + (l>>4)*8 + jj, j = cf*16 + (l&15)
// mode 0: B[k][j] = S[k*ldb + col0 + j]          (msg_W row-major)
// mode 1: B[k][j] = S[(row0 + j)*HH + k]         (GRU W [606][202], transposed use)
__global__ void pack_kernel(const float* __restrict__ S, int ldb, int row0, int col0, int mode,
                            unsigned short* __restrict__ BP) {
    int idx = blockIdx.x * blockDim.x + threadIdx.x;
    if (idx >= PKSZ) return;
    int jj = idx & 7;
    int l = (idx >> 3) & 63;
    int r2 = idx >> 9;             // cf*NKT + kt
    int cf = r2 / NKT, kt = r2 - cf * NKT;
    int k = kt * 32 + ((l >> 4) << 3) + jj;
    int j = cf * 16 + (l & 15);
    float v = 0.0f;
    if (k < HH && j < HH)
        v = mode ? S[(size_t)(row0 + j) * HH + k] : S[(size_t)k * ldb + col0 + j];
    BP[idx] = f2bf(v);
}

__global__ void count_kernel(const int* __restrict__ el, int* __restrict__ cnt) {
    int idx = blockIdx.x * blockDim.x + threadIdx.x;
    if (idx >= NEDG) return;
    int ty = idx / EE, e = idx - ty * EE;
    int2 pr = (ty < 3) ? reinterpret_cast<const int2*>(el)[ty * EE + e]
                       : reinterpret_cast<const int2*>(el)[(ty - 3) * EE + e];
    int tg = (ty < 3) ? pr.y : pr.x;
    atomicAdd(&cnt[tg], 1);
}

__global__ void scan1_kernel(const int* __restrict__ cnt, int* __restrict__ off,
                             int* __restrict__ bsum) {
    __shared__ int sd[256];
    int t = threadIdx.x, i = blockIdx.x * 256 + t;
    int v = (i < NN) ? cnt[i] : 0;
    sd[t] = v;
    __syncthreads();
    for (int s = 1; s < 256; s <<= 1) {
        int u = (t >= s) ? sd[t - s] : 0;
        __syncthreads();
        sd[t] += u;
        __syncthreads();
    }
    if (i < NN) off[i] = sd[t] - v;
    if (t == 255) bsum[blockIdx.x] = sd[255];
}

__global__ void scan2_kernel(int* __restrict__ bsum, int nb) {
    __shared__ int sd[256];
    int t = threadIdx.x;
    int v = (t < nb) ? bsum[t] : 0;
    sd[t] = v;
    __syncthreads();
    for (int s = 1; s < 256; s <<= 1) {
        int u = (t >= s) ? sd[t - s] : 0;
        __syncthreads();
        sd[t] += u;
        __syncthreads();
    }
    if (t < nb) bsum[t] = sd[t] - v;   // exclusive
}

__global__ void scan3_kernel(int* __restrict__ off, const int* __restrict__ bsum,
                             int* __restrict__ cursor) {
    int i = blockIdx.x * 256 + threadIdx.x;
    if (i < NN) {
        int o = off[i] + bsum[blockIdx.x];
        off[i] = o;
        cursor[i] = o;
    }
    if (i == 0) off[NN] = NEDG;
}

__global__ void inv_kernel(const int* __restrict__ cnt, float* __restrict__ inv) {
    int n = blockIdx.x * blockDim.x + threadIdx.x;
    if (n < NN) inv[n] = 1.0f / (float)max(cnt[n], 1);
}

// EDG[slot] = src(17b) << 13 | ty(3b) << 10 | pos(10b), grouped by target via cursor
__global__ void fill_kernel(const int* __restrict__ el, const int* __restrict__ pl,
                            int* __restrict__ cursor, int* __restrict__ edg) {
    int idx = blockIdx.x * blockDim.x + threadIdx.x;
    if (idx >= NEDG) return;
    int ty = idx / EE, e = idx - ty * EE;
    int s, tg;
    if (ty < 3) {
        int2 pr = reinterpret_cast<const int2*>(el)[ty * EE + e];
        s = pr.x; tg = pr.y;
    } else {
        int2 pr = reinterpret_cast<const int2*>(el)[(ty - 3) * EE + e];
        s = pr.y; tg = pr.x;
    }
    int p = pl[(ty % 3) * EE + e];
    p = min(max(p, 0), PMX - 1);
    int slot = atomicAdd(&cursor[tg], 1);
    edg[slot] = (s << 13) | (ty << 10) | p;
}

// chunks[ty][n][j] (bf16) for all 6 ty. M=64 tile; 4 waves column-split {4,3,3,3} cfs,
// each wave covers all 64 rows (4 row-frags) -> each B fragment feeds 4 MFMAs.
__global__ __launch_bounds__(256, 4) void prop_fused(
    const float* __restrict__ A, const unsigned short* __restrict__ BPp,
    const float* __restrict__ msg_b,
    unsigned short* __restrict__ CH0, unsigned short* __restrict__ CH45) {
    __shared__ unsigned short a_lds[64 * LDA];
    const int t = threadIdx.x;
    const int w = t >> 6;
    const int l = t & 63;
    const int lm = l & 15, lh = l >> 4;
    const int cs = w * 3 + (w > 0);     // 0,4,7,10
    const int ncf = w ? 3 : 4;
    const int base = blockIdx.x * 64;

    for (int idx = t; idx < 64 * 101; idx += 256) {
        int row = idx / 101;
        int c = idx - row * 101;
        int gn = base + row;
        float2 v = make_float2(0.f, 0.f);
        if (gn < NN) v = *reinterpret_cast<const float2*>(&A[(size_t)gn * HH + c * 2]);
        ushort2 bv; bv.x = f2bf(v.x); bv.y = f2bf(v.y);
        *reinterpret_cast<ushort2*>(&a_lds[row * LDA + c * 2]) = bv;
    }
    for (int idx = t; idx < 64 * 11; idx += 256) {
        int row = idx / 11;
        int c = idx - row * 11;
        ushort2 z; z.x = 0; z.y = 0;
        *reinterpret_cast<ushort2*>(&a_lds[row * LDA + HH + c * 2]) = z;
    }
    __syncthreads();

#pragma unroll 1
    for (int ty = 0; ty < 6; ++ty) {
        const unsigned short* BP = BPp + (size_t)ty * PKSZ;
        v4f acc[4][4];   // [ci][rf]
#pragma unroll
        for (int ci = 0; ci < 4; ++ci)
#pragma unroll
            for (int rf = 0; rf < 4; ++rf) acc[ci][rf] = (v4f){0.f, 0.f, 0.f, 0.f};

#pragma unroll 1
        for (int kt = 0; kt < NKT; ++kt) {
            short8 a[4];
#pragma unroll
            for (int rf = 0; rf < 4; ++rf)
                a[rf] = *reinterpret_cast<const short8*>(
                    &a_lds[(rf * 16 + lm) * LDA + kt * 32 + lh * 8]);
#pragma unroll
            for (int ci = 0; ci < 4; ++ci) {
                if (ci < ncf) {
                    short8 b = *reinterpret_cast<const short8*>(
                        &BP[((size_t)((cs + ci) * NKT + kt) * 64 + l) * 8]);
#pragma unroll
                    for (int rf = 0; rf < 4; ++rf)
                        acc[ci][rf] = __builtin_amdgcn_mfma_f32_16x16x32_bf16(
                            a[rf], b, acc[ci][rf], 0, 0, 0);
                }
            }
        }

        unsigned short* CH = (ty < 4) ? CH0 + (size_t)ty * NN * HH
                                      : CH45 + (size_t)(ty - 4) * NN * HH;
#pragma unroll
        for (int ci = 0; ci < 4; ++ci) {
            if (ci < ncf) {
                int col = (cs + ci) * 16 + lm;
                if (col < HH) {
                    float bb = msg_b[ty * HH + col];
#pragma unroll
                    for (int rf = 0; rf < 4; ++rf) {
#pragma unroll
                        for (int r = 0; r < 4; ++r) {
                            int row = base + rf * 16 + lh * 4 + r;
                            if (row < NN) CH[(size_t)row * HH + col] = f2bf(acc[ci][rf][r] + bb);
                        }
                    }
                }
            }
        }
    }
}

// one wave per target node: MSG[n] = inv[n] * sum_edges chunk[ty][src] * gate[pos]
__global__ void agg_kernel(const unsigned short* __restrict__ CH0,
                           const unsigned short* __restrict__ CH45,
                           const int* __restrict__ off, const int* __restrict__ edg,
                           const unsigned short* __restrict__ gate,
                           const float* __restrict__ inv, float* __restrict__ msg) {
    int n = blockIdx.x * 4 + (threadIdx.x >> 6);
    if (n >= NN) return;
    int lane = threadIdx.x & 63;
    int s0 = off[n], s1 = off[n + 1];
    int j0 = lane, j1 = lane + 64, j2 = lane + 128, j3 = lane + 192;
    float a0 = 0.f, a1 = 0.f, a2 = 0.f, a3 = 0.f;
    for (int i = s0; i < s1; ++i) {
        int rec = edg[i];
        int src = rec >> 13;
        int ty = (rec >> 10) & 7;
        int p = rec & 1023;
        const unsigned short* cr =
            ((ty < 4) ? CH0 + (size_t)ty * NN * HH : CH45 + (size_t)(ty - 4) * NN * HH)
            + (size_t)src * HH;
        const unsigned short* gr = gate + (size_t)p * HH;
        a0 += bf2f(cr[j0]) * bf2f(gr[j0]);
        a1 += bf2f(cr[j1]) * bf2f(gr[j1]);
        a2 += bf2f(cr[j2]) * bf2f(gr[j2]);
        if (j3 < HH) a3 += bf2f(cr[j3]) * bf2f(gr[j3]);
    }
    float iv = inv[n];
    float* mr = msg + (size_t)n * HH;
    mr[j0] = a0 * iv; mr[j1] = a1 * iv; mr[j2] = a2 * iv;
    if (j3 < HH) mr[j3] = a3 * iv;
}

// Fused GRU, 2-plane register schedule. M=64 tile; 4 waves column-split {4,3,3,3},
// each wave all 64 rows (4 row-frags). 4 sequential K-loops:
//   P1 = msg@Wir + h@Whr -> r = sig(P1+br)
//   P2 = h@Whn;  P2 = bin + r*(P2+bnh)
//   P2 += msg@Win  (MFMA C-in carries the pre-biased plane) -> n = tanh(P2)
//   P1 = msg@Wiz + h@Whz -> z; h' = (1-z)*n + z*h
__global__ __launch_bounds__(256, 2) void gru_fused(
    float* __restrict__ h, const float* __restrict__ msg,
    const unsigned short* __restrict__ BPir, const unsigned short* __restrict__ BPiz,
    const unsigned short* __restrict__ BPin, const unsigned short* __restrict__ BPhr,
    const unsigned short* __restrict__ BPhz, const unsigned short* __restrict__ BPhn,
    const float* __restrict__ bih, const float* __restrict__ bhh) {
    __shared__ unsigned short hl[64 * LDA];
    __shared__ unsigned short ml[64 * LDA];
    const int t = threadIdx.x;
    const int w = t >> 6;
    const int l = t & 63;
    const int lm = l & 15, lh = l >> 4;
    const int cs = w * 3 + (w > 0);     // 0,4,7,10
    const int ncf = w ? 3 : 4;
    const int base = blockIdx.x * 64;

    for (int idx = t; idx < 64 * 101; idx += 256) {
        int row = idx / 101;
        int c = idx - row * 101;
        int gn = base + row;
        float2 vh = make_float2(0.f, 0.f), vm = make_float2(0.f, 0.f);
        if (gn < NN) {
            vh = *reinterpret_cast<const float2*>(&h[(size_t)gn * HH + c * 2]);
            vm = *reinterpret_cast<const float2*>(&msg[(size_t)gn * HH + c * 2]);
        }
        ushort2 bh; bh.x = f2bf(vh.x); bh.y = f2bf(vh.y);
        ushort2 bm; bm.x = f2bf(vm.x); bm.y = f2bf(vm.y);
        *reinterpret_cast<ushort2*>(&hl[row * LDA + c * 2]) = bh;
        *reinterpret_cast<ushort2*>(&ml[row * LDA + c * 2]) = bm;
    }
    for (int idx = t; idx < 64 * 11; idx += 256) {
        int row = idx / 11;
        int c = idx - row * 11;
        ushort2 z; z.x = 0; z.y = 0;
        *reinterpret_cast<ushort2*>(&hl[row * LDA + HH + c * 2]) = z;
        *reinterpret_cast<ushort2*>(&ml[row * LDA + HH + c * 2]) = z;
    }
    __syncthreads();

    v4f P1[4][4], P2[4][4];
#pragma unroll
    for (int ci = 0; ci < 4; ++ci)
#pragma unroll
        for (int rf = 0; rf < 4; ++rf) P1[ci][rf] = (v4f){0.f, 0.f, 0.f, 0.f};

    // loop 1: P1 = msg@Wir + h@Whr
#pragma unroll 1
    for (int kt = 0; kt < NKT; ++kt) {
        short8 ah[4], am[4];
#pragma unroll
        for (int rf = 0; rf < 4; ++rf) {
            ah[rf] = *reinterpret_cast<const short8*>(&hl[(rf * 16 + lm) * LDA + kt * 32 + lh * 8]);
            am[rf] = *reinterpret_cast<const short8*>(&ml[(rf * 16 + lm) * LDA + kt * 32 + lh * 8]);
        }
#pragma unroll
        for (int ci = 0; ci < 4; ++ci) {
            if (ci < ncf) {
                size_t bo = ((size_t)((cs + ci) * NKT + kt) * 64 + l) * 8;
                short8 bir = *reinterpret_cast<const short8*>(&BPir[bo]);
                short8 bhr = *reinterpret_cast<const short8*>(&BPhr[bo]);
#pragma unroll
                for (int rf = 0; rf < 4; ++rf) {
                    P1[ci][rf] = __builtin_amdgcn_mfma_f32_16x16x32_bf16(am[rf], bir, P1[ci][rf], 0, 0, 0);
                    P1[ci][rf] = __builtin_amdgcn_mfma_f32_16x16x32_bf16(ah[rf], bhr, P1[ci][rf], 0, 0, 0);
                }
            }
        }
    }
    // r = sig(P1 + br)
#pragma unroll
    for (int ci = 0; ci < 4; ++ci) {
        if (ci < ncf) {
            int col = (cs + ci) * 16 + lm;
            float br = (col < HH) ? (bih[col] + bhh[col]) : 0.f;
#pragma unroll
            for (int rf = 0; rf < 4; ++rf)
#pragma unroll
                for (int r = 0; r < 4; ++r)
                    P1[ci][rf][r] = sigf(P1[ci][rf][r] + br);
        }
    }

    // loop 2: P2 = h@Whn
#pragma unroll
    for (int ci = 0; ci < 4; ++ci)
#pragma unroll
        for (int rf = 0; rf < 4; ++rf) P2[ci][rf] = (v4f){0.f, 0.f, 0.f, 0.f};
#pragma unroll 1
    for (int kt = 0; kt < NKT; ++kt) {
        short8 ah[4];
#pragma unroll
        for (int rf = 0; rf < 4; ++rf)
            ah[rf] = *reinterpret_cast<const short8*>(&hl[(rf * 16 + lm) * LDA + kt * 32 + lh * 8]);
#pragma unroll
        for (int ci = 0; ci < 4; ++ci) {
            if (ci < ncf) {
                size_t bo = ((size_t)((cs + ci) * NKT + kt) * 64 + l) * 8;
                short8 bhn = *reinterpret_cast<const short8*>(&BPhn[bo]);
#pragma unroll
                for (int rf = 0; rf < 4; ++rf)
                    P2[ci][rf] = __builtin_amdgcn_mfma_f32_16x16x32_bf16(ah[rf], bhn, P2[ci][rf], 0, 0, 0);
            }
        }
    }
    // P2 = bin + r*(P2 + bnh)
#pragma unroll
    for (int ci = 0; ci < 4; ++ci) {
        if (ci < ncf) {
            int col = (cs + ci) * 16 + lm;
            float bn_i = (col < HH) ? bih[404 + col] : 0.f;
            float bn_h = (col < HH) ? bhh[404 + col] : 0.f;
#pragma unroll
            for (int rf = 0; rf < 4; ++rf)
#pragma unroll
                for (int r = 0; r < 4; ++r)
                    P2[ci][rf][r] = bn_i + P1[ci][rf][r] * (P2[ci][rf][r] + bn_h);
        }
    }

    // loop 3: P2 += msg@Win; then n = tanh(P2)
#pragma unroll 1
    for (int kt = 0; kt < NKT; ++kt) {
        short8 am[4];
#pragma unroll
        for (int rf = 0; rf < 4; ++rf)
            am[rf] = *reinterpret_cast<const short8*>(&ml[(rf * 16 + lm) * LDA + kt * 32 + lh * 8]);
#pragma unroll
        for (int ci = 0; ci < 4; ++ci) {
            if (ci < ncf) {
                size_t bo = ((size_t)((cs + ci) * NKT + kt) * 64 + l) * 8;
                short8 bin_ = *reinterpret_cast<const short8*>(&BPin[bo]);
#pragma unroll
                for (int rf = 0; rf < 4; ++rf)
                    P2[ci][rf] = __builtin_amdgcn_mfma_f32_16x16x32_bf16(am[rf], bin_, P2[ci][rf], 0, 0, 0);
            }
        }
    }
#pragma unroll
    for (int ci = 0; ci < 4; ++ci)
        if (ci < ncf)
#pragma unroll
            for (int rf = 0; rf < 4; ++rf)
#pragma unroll
                for (int r = 0; r < 4; ++r)
                    P2[ci][rf][r] = tanhf(P2[ci][rf][r]);

    // loop 4: P1 = msg@Wiz + h@Whz
#pragma unroll
    for (int ci = 0; ci < 4; ++ci)
#pragma unroll
        for (int rf = 0; rf < 4; ++rf) P1[ci][rf] = (v4f){0.f, 0.f, 0.f, 0.f};
#pragma unroll 1
    for (int kt = 0; kt < NKT; ++kt) {
        short8 ah[4], am[4];
#pragma unroll
        for (int rf = 0; rf < 4; ++rf) {
            ah[rf] = *reinterpret_cast<const short8*>(&hl[(rf * 16 + lm) * LDA + kt * 32 + lh * 8]);
            am[rf] = *reinterpret_cast<const short8*>(&ml[(rf * 16 + lm) * LDA + kt * 32 + lh * 8]);
        }
#pragma unroll
        for (int ci = 0; ci < 4; ++ci) {
            if (ci < ncf) {
                size_t bo = ((size_t)((cs + ci) * NKT + kt) * 64 + l) * 8;
                short8 biz = *reinterpret_cast<const short8*>(&BPiz[bo]);
                short8 bhz = *reinterpret_cast<const short8*>(&BPhz[bo]);
#pragma unroll
                for (int rf = 0; rf < 4; ++rf) {
                    P1[ci][rf] = __builtin_amdgcn_mfma_f32_16x16x32_bf16(am[rf], biz, P1[ci][rf], 0, 0, 0);
                    P1[ci][rf] = __builtin_amdgcn_mfma_f32_16x16x32_bf16(ah[rf], bhz, P1[ci][rf], 0, 0, 0);
                }
            }
        }
    }

    // z = sig(P1+bz); h' = (1-z)*n + z*h
#pragma unroll
    for (int ci = 0; ci < 4; ++ci) {
        if (ci < ncf) {
            int col = (cs + ci) * 16 + lm;
            if (col < HH) {
                float bz = bih[202 + col] + bhh[202 + col];
#pragma unroll
                for (int rf = 0; rf < 4; ++rf) {
#pragma unroll
                    for (int r = 0; r < 4; ++r) {
                        int row = base + rf * 16 + lh * 4 + r;
                        if (row < NN) {
                            float z = sigf(P1[ci][rf][r] + bz);
                            float hv = h[(size_t)row * HH + col];
                            h[(size_t)row * HH + col] = (1.0f - z) * P2[ci][rf][r] + z * hv;
                        }
                    }
                }
            }
        }
    }
}

extern "C" void kernel_launch(void* const* d_in, const int* in_sizes, int n_in,
                              void* d_out, int out_size, void* d_ws, size_t ws_size,
                              hipStream_t stream) {
    const float* node_states = (const float*)d_in[0];
    const int*   el          = (const int*)d_in[1];
    const int*   pl          = (const int*)d_in[2];
    const float* msg_W       = (const float*)d_in[3];
    const float* msg_b       = (const float*)d_in[4];
    const float* pos_W       = (const float*)d_in[5];
    const float* pos_b       = (const float*)d_in[6];
    const float* gWih        = (const float*)d_in[7];
    const float* gWhh        = (const float*)d_in[8];
    const float* gbih        = (const float*)d_in[9];
    const float* gbhh        = (const float*)d_in[10];

    float* out  = (float*)d_out;
    float* h    = out;                               // [N,H] final h
    float* out2 = out + (size_t)NN * HH;             // chunks ty=4,5 during steps; node_states at end

    unsigned short* CH0  = (unsigned short*)d_ws;                    // 4 slabs bf16 [N,H]
    unsigned short* CH45 = (unsigned short*)out2;                    // 2 slabs bf16 [N,H]
    float* MSG  = (float*)(CH0 + (size_t)4 * NN * HH);               // [N,H] f32
    unsigned short* GATE = (unsigned short*)(MSG + (size_t)NN * HH); // [1024,H] bf16
    float* INV  = (float*)(GATE + (size_t)PMX * HH);                 // [N]
    int* CNT    = (int*)(INV + NN);                                  // [N]
    int* OFF    = CNT + NN;                                          // [N+4]
    int* CUR    = OFF + NN + 4;                                      // [N]
    int* BS     = CUR + NN;                                          // [256]
    int* EDG    = BS + 256;                                          // [600000]
    unsigned short* BPA = (unsigned short*)(EDG + NEDG);             // 12 packs
    unsigned short* BPp  = BPA;
    unsigned short* BPir = BPA + (size_t)6 * PKSZ;
    unsigned short* BPiz = BPA + (size_t)7 * PKSZ;
    unsigned short* BPin = BPA + (size_t)8 * PKSZ;
    unsigned short* BPhr = BPA + (size_t)9 * PKSZ;
    unsigned short* BPhz = BPA + (size_t)10 * PKSZ;
    unsigned short* BPhn = BPA + (size_t)11 * PKSZ;

    const size_t NH = (size_t)NN * HH;
    hipMemcpyAsync(h, node_states, NH * sizeof(float), hipMemcpyDeviceToDevice, stream);
    hipMemsetAsync(CNT, 0, NN * sizeof(int), stream);
    gate_kernel<<<PMX, 256, 0, stream>>>(pos_W, pos_b, GATE);
    const int pkb = (PKSZ + 255) / 256;
    for (int ty = 0; ty < 6; ++ty)
        pack_kernel<<<pkb, 256, 0, stream>>>(msg_W, 1212, 0, ty * HH, 0, BPp + (size_t)ty * PKSZ);
    pack_kernel<<<pkb, 256, 0, stream>>>(gWih, 0, 0,   0, 1, BPir);
    pack_kernel<<<pkb, 256, 0, stream>>>(gWih, 0, 202, 0, 1, BPiz);
    pack_kernel<<<pkb, 256, 0, stream>>>(gWih, 0, 404, 0, 1, BPin);
    pack_kernel<<<pkb, 256, 0, stream>>>(gWhh, 0, 0,   0, 1, BPhr);
    pack_kernel<<<pkb, 256, 0, stream>>>(gWhh, 0, 202, 0, 1, BPhz);
    pack_kernel<<<pkb, 256, 0, stream>>>(gWhh, 0, 404, 0, 1, BPhn);

    const int nsb = (NN + 255) / 256;    // 196
    count_kernel<<<(NEDG + 255) / 256, 256, 0, stream>>>(el, CNT);
    scan1_kernel<<<nsb, 256, 0, stream>>>(CNT, OFF, BS);
    scan2_kernel<<<1, 256, 0, stream>>>(BS, nsb);
    scan3_kernel<<<nsb, 256, 0, stream>>>(OFF, BS, CUR);
    inv_kernel<<<nsb, 256, 0, stream>>>(CNT, INV);
    fill_kernel<<<(NEDG + 255) / 256, 256, 0, stream>>>(el, pl, CUR, EDG);

    for (int step = 0; step < 2; ++step) {
        prop_fused<<<(NN + 63) / 64, 256, 0, stream>>>(h, BPp, msg_b, CH0, CH45);
        agg_kernel<<<(NN + 3) / 4, 256, 0, stream>>>(CH0, CH45, OFF, EDG, GATE, INV, MSG);
        gru_fused<<<(NN + 63) / 64, 256, 0, stream>>>(h, MSG, BPir, BPiz, BPin,
                                                      BPhr, BPhz, BPhn, gbih, gbhh);
    }
    hipMemcpyAsync(out2, node_states, NH * sizeof(float), hipMemcpyDeviceToDevice, stream);
}